// Round 3
// baseline (386.275 us; speedup 1.0000x reference)
//
#include <hip/hip_runtime.h>

#define MD 8192
#define ND 8192
#define DD 256
#define KTOP 256
#define CAND_T0 0.26f
#define NCAP 4096
#define NPAD 4096

typedef unsigned int u32;
typedef unsigned short u16;
typedef unsigned long long u64;

// workspace layout (bytes)
#define OFF_R    0                  // double R[8192]          64 KB
#define OFF_CP   65536              // double CP[8][8192]     512 KB
#define OFF_CNT  589824             // int
#define OFF_CAND 589952             // u32 cand[4096]          16 KB
#define OFF_KEYS 606336             // u64 keys[4096]          32 KB
#define OFF_A16  655360             // u16 A16[8192*256]        4 MB
#define OFF_B16  (OFF_A16 + 4194304)
#define WS_REQ   (OFF_B16 + 4194304)

using f16x8 = __attribute__((ext_vector_type(8))) _Float16;
using f32x4  = __attribute__((ext_vector_type(4))) float;

#define AS1 __attribute__((address_space(1)))
#define AS3 __attribute__((address_space(3)))

__device__ __forceinline__ u16 f2h(float x) {
  union { _Float16 h; u16 u; } v;
  v.h = (_Float16)x;   // v_cvt_f16_f32, RNE
  return v.u;
}

// fallback-path init: zero R, CP, cnt (grid-stride)
__global__ void k_init(double* __restrict__ R, double* __restrict__ CP, int* __restrict__ cnt) {
  int stride = gridDim.x * blockDim.x;
  for (int i = blockIdx.x * blockDim.x + threadIdx.x; i < MD + 8 * ND; i += stride) {
    if (i < MD) R[i] = 0.0;
    else CP[i - MD] = 0.0;
  }
  if (blockIdx.x == 0 && threadIdx.x == 0) *cnt = 0;
}

// Fused: zero R/CP/cnt + convert BOTH matrices to single fp16 planes.
// R12: fp16 single-product (verified absmax 0; gemm 135 -> 65 us). c only
// feeds the cand threshold (noise 1.2e-5 << 0.26 margin) and row/col sums
// (per-term e-error 2.4e-5 averages to ~2.7e-7 on the sum); top-256
// numerators recomputed exactly in fp64 by k_score.
__global__ __launch_bounds__(256) void k_prep2(
    const float* __restrict__ A, const float* __restrict__ B,
    u16* __restrict__ A16p, u16* __restrict__ B16p,
    double* __restrict__ R, double* __restrict__ CP, int* __restrict__ cnt) {
  const int gid = blockIdx.x * 256 + threadIdx.x;
  if (gid < MD) R[gid] = 0.0;
  if (gid < 8 * ND) CP[gid] = 0.0;
  if (gid == 0) *cnt = 0;

  {
    float4 v = ((const float4*)A)[gid];
    ushort4 h;
    h.x = f2h(v.x); h.y = f2h(v.y); h.z = f2h(v.z); h.w = f2h(v.w);
    ((ushort4*)A16p)[gid] = h;
  }
  {
    float4 v = ((const float4*)B)[gid];
    ushort4 h;
    h.x = f2h(v.x); h.y = f2h(v.y); h.z = f2h(v.z); h.w = f2h(v.w);
    ((ushort4*)B16p)[gid] = h;
  }
}

// ---------------- MFMA fp16 GEMM (R14: 256x256 tile, 8 waves) --------------
// R14 vs R13 (gemm 63 us, MfmaUtil 21%): R13's dbuf prefetch was neutral
// because the 128x128 compute phase (~350 cy) < load latency (~300-900 cy)
// — regime gate (learn_hip rule #23). 256x256 / 8 waves (2x4) fixes the
// ratio structurally:
//   - per-wave tile 128x64: 32 MFMA per 12 ds_read_b128 (was 16/8) -> LDS
//     read cycles (the binding pipe, ~49k cy/CU) drop 25%.
//   - 256 MFMA per block-step (~1200 cy) >> load latency -> the dbuf
//     prefetch finally hides the staging.
//   - 1024 blocks instead of 4096: halved logical fetch, better L2.
// LDS 70 KB -> 2 blocks/CU (16 waves). Staging swizzle identical
// per-64-row-half to the proven conflict-free pattern (R5/R9: 0 conflicts).
__global__ __launch_bounds__(512, 4) void k_gemm_mfma(
    const u16* __restrict__ A16, const u16* __restrict__ B16,
    double* __restrict__ R, double* __restrict__ CP,
    int* __restrict__ cnt, u32* __restrict__ cand, int ncap) {
  __shared__ u16 sA[2][256][32];      // 32 KB
  __shared__ u16 sB[2][256][32];      // 32 KB
  __shared__ float sRcomb[4][2][128]; // 4 KB  [wcol][wrow][i*16+quad*4+r]
  __shared__ double sCcomb[4][64];    // 2 KB  [wcol][j*16+lo]  from wrow==1

  const int tid = threadIdx.x;
  const int lane = tid & 63;
  const int wid = tid >> 6;            // 0..7
  const int wrow = wid >> 2;           // 0..1  (128-row half)
  const int wcol = wid & 3;            // 0..3  (64-col quarter)

  // XCD-aware block swizzle (1-D grid of 1024; 1024%8==0 -> bijective)
  const int g = blockIdx.x;
  const int xcd = g & 7;
  const int l = g >> 3;                // 0..127
  const int rowTile = xcd * 4 + (l & 3);   // 0..31
  const int colTile = l >> 2;              // 0..31
  const int rowBase = rowTile * 256;
  const int colBase = colTile * 256;
  double* Cmy = CP + (size_t)xcd * ND;

  const int quad = lane >> 4, lo = lane & 15;
  const int sw = (lo >> 1) & 3;
  const int cswz = (lane & 3) ^ ((lane >> 3) & 3);

  // staging: waves 0-3 -> sA 64-row quarters; waves 4-7 -> sB quarters.
  // Each wave: 4 chunks of 16 rows; per-lane row = lane>>2, col = cswz*8.
  u16* lb0;
  const u16* gbl;
  if (wid < 4) {
    lb0 = &sA[0][wid * 64][0];
    gbl = A16 + (size_t)(rowBase + wid * 64 + (lane >> 2)) * DD + cswz * 8;
  } else {
    lb0 = &sB[0][(wid - 4) * 64][0];
    gbl = B16 + (size_t)(colBase + (wid - 4) * 64 + (lane >> 2)) * DD + cswz * 8;
  }

  // Buffer stride: sA[1]-sA[0] = 256*32 = 8192 u16 (same for sB).
#define STAGE(b, kt) \
  do { \
    _Pragma("unroll") \
    for (int ch = 0; ch < 4; ++ch) { \
      const u16* gp = gbl + (size_t)(ch * 16) * DD + (kt) * 32; \
      __builtin_amdgcn_global_load_lds((const AS1 void*)gp, \
          (AS3 void*)(lb0 + (b) * 8192 + ch * 512), 16, 0, 0); \
    } \
  } while (0)

  f32x4 acc[8][4];
#pragma unroll
  for (int i = 0; i < 8; ++i)
#pragma unroll
    for (int j = 0; j < 4; ++j) acc[i][j] = (f32x4){0.f, 0.f, 0.f, 0.f};

  const int cq = (quad ^ sw) * 8;

  STAGE(0, 0);
  __syncthreads();   // drain prologue loads

#pragma unroll
  for (int kt = 0; kt < 8; ++kt) {
    const int cur = kt & 1;
    if (kt < 7) STAGE(cur ^ 1, kt + 1);   // flies under ~1200 cy of compute

    f16x8 fa[8];
#pragma unroll
    for (int t = 0; t < 8; ++t)
      fa[t] = *(const f16x8*)&sA[cur][wrow * 128 + t * 16 + lo][cq];
#pragma unroll
    for (int j = 0; j < 4; ++j) {
      f16x8 fb = *(const f16x8*)&sB[cur][wcol * 64 + j * 16 + lo][cq];
#pragma unroll
      for (int i = 0; i < 8; ++i)
        acc[i][j] = __builtin_amdgcn_mfma_f32_16x16x32_f16(fa[i], fb, acc[i][j], 0, 0, 0);
    }
    __syncthreads();
  }
#undef STAGE

  // epilogue: e = exp(2c-2); row partials fp32, col partials fp64; candidates.
  // C/D layout: col = lo, row = quad*4 + reg  (m89/m91)
  float rowp[8][4];
  double colp[4];
#pragma unroll
  for (int i = 0; i < 8; ++i)
#pragma unroll
    for (int r = 0; r < 4; ++r) rowp[i][r] = 0.f;
#pragma unroll
  for (int j = 0; j < 4; ++j) colp[j] = 0.0;

#pragma unroll
  for (int i = 0; i < 8; ++i)
#pragma unroll
    for (int j = 0; j < 4; ++j)
#pragma unroll
      for (int r = 0; r < 4; ++r) {
        float c = acc[i][j][r];
        float e = __expf(2.f * c - 2.f);
        rowp[i][r] += e;
        colp[j] += (double)e;
        if (c >= CAND_T0) {
          int row = rowBase + wrow * 128 + i * 16 + quad * 4 + r;
          int col = colBase + wcol * 64 + j * 16 + lo;
          int idx = atomicAdd(cnt, 1);
          if (idx < ncap) cand[idx] = ((u32)row << 13) | (u32)col;
        }
      }

  // row sums: reduce over lo (16 lanes) -> sum over this wave's 64 cols
#pragma unroll
  for (int i = 0; i < 8; ++i)
#pragma unroll
    for (int r = 0; r < 4; ++r) {
      float v = rowp[i][r];
#pragma unroll
      for (int off = 8; off; off >>= 1) v += __shfl_xor(v, off, 16);
      rowp[i][r] = v;
    }
  // col sums: reduce over quad -> sum over this wave's 128 rows
#pragma unroll
  for (int j = 0; j < 4; ++j) {
    double v = colp[j];
    v += __shfl_xor(v, 16);
    v += __shfl_xor(v, 32);
    colp[j] = v;
  }

  // cross-wave combine: 4 wcol partials per row, 2 wrow partials per col
  if (wcol && lo == 0) {
#pragma unroll
    for (int i = 0; i < 8; ++i)
#pragma unroll
      for (int r = 0; r < 4; ++r)
        sRcomb[wcol][wrow][i * 16 + quad * 4 + r] = rowp[i][r];
  }
  if (wrow == 1 && quad == 0) {
#pragma unroll
    for (int j = 0; j < 4; ++j) sCcomb[wcol][j * 16 + lo] = colp[j];
  }
  __syncthreads();

  if (wcol == 0 && lo == 0) {
#pragma unroll
    for (int i = 0; i < 8; ++i)
#pragma unroll
      for (int r = 0; r < 4; ++r) {
        int idx = i * 16 + quad * 4 + r;
        float tot = rowp[i][r] + sRcomb[1][wrow][idx] + sRcomb[2][wrow][idx]
                  + sRcomb[3][wrow][idx];
        atomicAdd(&R[rowBase + wrow * 128 + idx], (double)tot);
      }
  }
  if (wrow == 0 && quad == 0) {
#pragma unroll
    for (int j = 0; j < 4; ++j) {
      int idx = j * 16 + lo;
      atomicAdd(&Cmy[colBase + wcol * 64 + idx], colp[j] + sCcomb[wcol][idx]);
    }
  }
}

// ---------------- fp32 fallback GEMM (used only if ws too small) ----------------
__global__ __launch_bounds__(256) void k_gemm_f32(
    const float* __restrict__ A, const float* __restrict__ B,
    double* __restrict__ R, double* __restrict__ CP,
    int* __restrict__ cnt, u32* __restrict__ cand, int ncap) {
  __shared__ float As[32][128];
  __shared__ float Bs[32][128];
  __shared__ double colLds[16][128];
  const int tid = threadIdx.x;
  const int tx = tid & 15, ty = tid >> 4;
  const int rowBase = blockIdx.y * 128;
  const int colBase = blockIdx.x * 128;
  float acc[8][8];
#pragma unroll
  for (int i = 0; i < 8; ++i)
#pragma unroll
    for (int j = 0; j < 8; ++j) acc[i][j] = 0.f;
  const int lr = tid >> 3;
  const int lc = (tid & 7) << 2;
  for (int kk = 0; kk < DD; kk += 32) {
#pragma unroll
    for (int r = 0; r < 4; ++r) {
      int row = lr + r * 32;
      float4 av = *(const float4*)(A + (size_t)(rowBase + row) * DD + kk + lc);
      float4 bv = *(const float4*)(B + (size_t)(colBase + row) * DD + kk + lc);
      As[lc + 0][row] = av.x; As[lc + 1][row] = av.y; As[lc + 2][row] = av.z; As[lc + 3][row] = av.w;
      Bs[lc + 0][row] = bv.x; Bs[lc + 1][row] = bv.y; Bs[lc + 2][row] = bv.z; Bs[lc + 3][row] = bv.w;
    }
    __syncthreads();
#pragma unroll 4
    for (int k = 0; k < 32; ++k) {
      float a[8], b[8];
      *(float4*)(a + 0) = *(const float4*)(&As[k][ty * 8 + 0]);
      *(float4*)(a + 4) = *(const float4*)(&As[k][ty * 8 + 4]);
      *(float4*)(b + 0) = *(const float4*)(&Bs[k][tx * 8 + 0]);
      *(float4*)(b + 4) = *(const float4*)(&Bs[k][tx * 8 + 4]);
#pragma unroll
      for (int i = 0; i < 8; ++i)
#pragma unroll
        for (int j = 0; j < 8; ++j)
          acc[i][j] = fmaf(a[i], b[j], acc[i][j]);
    }
    __syncthreads();
  }
  double colpart[8];
#pragma unroll
  for (int j = 0; j < 8; ++j) colpart[j] = 0.0;
#pragma unroll
  for (int i = 0; i < 8; ++i) {
    double rp = 0.0;
#pragma unroll
    for (int j = 0; j < 8; ++j) {
      float e = __expf(2.f * acc[i][j] - 2.f);
      rp += (double)e;
      colpart[j] += (double)e;
    }
#pragma unroll
    for (int off = 8; off; off >>= 1) rp += __shfl_down(rp, off, 16);
    if (tx == 0) atomicAdd(&R[rowBase + ty * 8 + i], rp);
  }
#pragma unroll
  for (int j = 0; j < 8; ++j) colLds[ty][tx * 8 + j] = colpart[j];
  __syncthreads();
  if (tid < 128) {
    double s = 0.0;
#pragma unroll
    for (int t = 0; t < 16; ++t) s += colLds[t][tid];
    atomicAdd(&CP[colBase + tid], s);   // partition 0 only
  }
#pragma unroll
  for (int i = 0; i < 8; ++i)
#pragma unroll
    for (int j = 0; j < 8; ++j) {
      if (acc[i][j] >= CAND_T0) {
        int idx = atomicAdd(cnt, 1);
        if (idx < ncap)
          cand[idx] = ((u32)(rowBase + ty * 8 + i) << 13) | (u32)(colBase + tx * 8 + j);
      }
    }
}

// One wave per candidate: exact fp64 dot, fp64 score, orderable u64 key.
__global__ __launch_bounds__(256) void k_score(
    const float* __restrict__ A, const float* __restrict__ B,
    const double* __restrict__ R, const double* __restrict__ CP,
    const int* __restrict__ cnt, const u32* __restrict__ cand,
    u64* __restrict__ keys, int ncap) {
  int w = (int)((blockIdx.x * 256 + threadIdx.x) >> 6);
  int lane = threadIdx.x & 63;
  int n = *cnt; if (n > ncap) n = ncap;
  if (w >= n) return;
  u32 mn = cand[w];
  int m = (int)(mn >> 13), nn = (int)(mn & 8191u);
  const float* ar = A + (size_t)m * DD;
  const float* br = B + (size_t)nn * DD;
  double s = 0.0;
#pragma unroll
  for (int d = 0; d < DD; d += 64)
    s = fma((double)ar[d + lane], (double)br[d + lane], s);
#pragma unroll
  for (int off = 32; off; off >>= 1) s += __shfl_down(s, off);
  if (lane == 0) {
    double Cn = 0.0;
#pragma unroll
    for (int x = 0; x < 8; ++x) Cn += CP[(size_t)x * ND + nn];
    double sc = exp(4.0 * s - 4.0) / (R[m] * Cn);
    keys[w] = (u64)__double_as_longlong(sc);
  }
}

// (key desc, flat-idx asc) strict order; idx unique so no true ties.
__device__ __forceinline__ bool is_worse(u64 ka, u32 ma, u64 kb, u32 mb) {
  return (ka < kb) || (ka == kb && ma > mb);
}

// Single-block top-256: register/shuffle bitonic. Fast path n<=2048, with
// dynamic merge depth (np=1024 when n<=1024 -> skip one bitonic level).
// Legacy 4096 LDS bitonic fallback.
__global__ __launch_bounds__(1024) void k_sort(
    const int* __restrict__ cnt, const u32* __restrict__ cand,
    const u64* __restrict__ keys, float* __restrict__ out, int ncap) {
  __shared__ u64 sk[NPAD];
  __shared__ u32 sm[NPAD];
  const int tid = threadIdx.x;
  const int lane = tid & 63;
  const int wid = tid >> 6;
  int m = *cnt; if (m > ncap) m = ncap;

  if (m <= 2048) {
    const int NP = (m <= 1024) ? 1024 : 2048;
    const int base = wid * 128;
    const int i0 = base + lane * 2;

    // wave-local sort of each 128-segment (reg/shuffle, zero barriers).
    // Padding segments (>= NP) sort trivially and are never merged/read.
    u64 k0 = (i0 < m) ? keys[i0] : 0;
    u64 k1 = (i0 + 1 < m) ? keys[i0 + 1] : 0;
    u32 m0 = (i0 < m) ? cand[i0] : 0xFFFFFFFFu;
    u32 m1 = (i0 + 1 < m) ? cand[i0 + 1] : 0xFFFFFFFFu;
#pragma unroll
    for (int k = 2; k <= 128; k <<= 1) {
#pragma unroll
      for (int j = k >> 1; j >= 1; j >>= 1) {
        const bool bf = ((i0 & k) == 0);
        if (j == 1) {
          bool sw = bf ? is_worse(k0, m0, k1, m1) : is_worse(k1, m1, k0, m0);
          if (sw) { u64 tk = k0; k0 = k1; k1 = tk; u32 tm = m0; m0 = m1; m1 = tm; }
        } else {
          const int j2 = j >> 1;
          const bool keepb = (bf == ((lane & j2) == 0));
          u64 pk0 = __shfl_xor(k0, j2); u32 pm0 = __shfl_xor(m0, j2);
          u64 pk1 = __shfl_xor(k1, j2); u32 pm1 = __shfl_xor(m1, j2);
          if (keepb == is_worse(k0, m0, pk0, pm0)) { k0 = pk0; m0 = pm0; }
          if (keepb == is_worse(k1, m1, pk1, pm1)) { k1 = pk1; m1 = pm1; }
        }
      }
    }
    sk[i0] = k0; sk[i0 + 1] = k1; sm[i0] = m0; sm[i0 + 1] = m1;
    __syncthreads();

    for (int k = 256; k <= NP; k <<= 1) {
      for (int j = k >> 1; j >= 128; j >>= 1) {
        for (int i = tid; i < NP; i += 1024) {
          int l = i ^ j;
          if (l > i) {
            u64 ki = sk[i], kl = sk[l];
            u32 mi = sm[i], ml = sm[l];
            bool bf = ((i & k) == 0);
            bool swp = bf ? is_worse(ki, mi, kl, ml) : is_worse(kl, ml, ki, mi);
            if (swp) { sk[i] = kl; sk[l] = ki; sm[i] = ml; sm[l] = mi; }
          }
        }
        __syncthreads();
      }
      if (i0 < NP) {
        k0 = sk[i0]; k1 = sk[i0 + 1]; m0 = sm[i0]; m1 = sm[i0 + 1];
        const bool bf = ((base & k) == 0);
#pragma unroll
        for (int j = 64; j >= 2; j >>= 1) {
          const int j2 = j >> 1;
          const bool keepb = (bf == ((lane & j2) == 0));
          u64 pk0 = __shfl_xor(k0, j2); u32 pm0 = __shfl_xor(m0, j2);
          u64 pk1 = __shfl_xor(k1, j2); u32 pm1 = __shfl_xor(m1, j2);
          if (keepb == is_worse(k0, m0, pk0, pm0)) { k0 = pk0; m0 = pm0; }
          if (keepb == is_worse(k1, m1, pk1, pm1)) { k1 = pk1; m1 = pm1; }
        }
        {
          bool sw = bf ? is_worse(k0, m0, k1, m1) : is_worse(k1, m1, k0, m0);
          if (sw) { u64 tk = k0; k0 = k1; k1 = tk; u32 tm = m0; m0 = m1; m1 = tm; }
        }
      }
      __syncthreads();
      if (i0 < NP) { sk[i0] = k0; sk[i0 + 1] = k1; sm[i0] = m0; sm[i0 + 1] = m1; }
      __syncthreads();
    }
  } else {
    for (int i = tid; i < NPAD; i += 1024) { sk[i] = 0; sm[i] = 0xFFFFFFFFu; }
    __syncthreads();
    for (int i = tid; i < m; i += 1024) { sk[i] = keys[i]; sm[i] = cand[i]; }
    __syncthreads();
    for (unsigned k = 2; k <= (unsigned)NPAD; k <<= 1) {
      for (unsigned j = k >> 1; j > 0; j >>= 1) {
        for (unsigned i = tid; i < (unsigned)NPAD; i += 1024) {
          unsigned l = i ^ j;
          if (l > i) {
            u64 ki = sk[i], kl = sk[l];
            u32 mi = sm[i], ml = sm[l];
            bool dir = ((i & k) == 0);
            bool swp = dir ? is_worse(ki, mi, kl, ml) : is_worse(kl, ml, ki, mi);
            if (swp) { sk[i] = kl; sk[l] = ki; sm[i] = ml; sm[l] = mi; }
          }
        }
        __syncthreads();
      }
    }
  }

  for (int r = tid; r < KTOP; r += 1024) {
    u32 mn = sm[r];
    u64 kk = sk[r];
    out[r] = (float)(mn >> 13);
    out[KTOP + r] = (float)(mn & 8191u);
    out[2 * KTOP + r] = (float)__longlong_as_double((long long)kk);
  }
}

extern "C" void kernel_launch(void* const* d_in, const int* in_sizes, int n_in,
                              void* d_out, int out_size, void* d_ws, size_t ws_size,
                              hipStream_t stream) {
  (void)in_sizes; (void)n_in; (void)out_size;
  const float* A = (const float*)d_in[0];  // ref_feats [8192,256]
  const float* B = (const float*)d_in[1];  // src_feats [8192,256]
  float* out = (float*)d_out;
  char* ws = (char*)d_ws;
  double* R = (double*)(ws + OFF_R);
  double* CP = (double*)(ws + OFF_CP);
  int* cnt = (int*)(ws + OFF_CNT);
  u32* cand = (u32*)(ws + OFF_CAND);
  u64* keys = (u64*)(ws + OFF_KEYS);

  if (ws_size >= (size_t)WS_REQ) {
    u16* A16p = (u16*)(ws + OFF_A16);
    u16* B16p = (u16*)(ws + OFF_B16);
    hipLaunchKernelGGL(k_prep2, dim3(2048), dim3(256), 0, stream,
                       A, B, A16p, B16p, R, CP, cnt);
    hipLaunchKernelGGL(k_gemm_mfma, dim3(1024), dim3(512), 0, stream,
                       A16p, B16p, R, CP, cnt, cand, NCAP);
  } else {
    hipLaunchKernelGGL(k_init, dim3(288), dim3(256), 0, stream, R, CP, cnt);
    hipLaunchKernelGGL(k_gemm_f32, dim3(ND / 128, MD / 128), dim3(256), 0, stream,
                       A, B, R, CP, cnt, cand, NCAP);
  }

  hipLaunchKernelGGL(k_score, dim3(NCAP / 4), dim3(256), 0, stream,
                     A, B, R, CP, cnt, cand, keys, NCAP);
  hipLaunchKernelGGL(k_sort, dim3(1), dim3(1024), 0, stream,
                     cnt, cand, keys, out, NCAP);
}

// Round 4
// 151.169 us; speedup vs baseline: 2.5553x; 2.5553x over previous
//
#include <hip/hip_runtime.h>

#define MD 8192
#define ND 8192
#define DD 256
#define KTOP 256
#define CAND_T0 0.26f
#define NCAP 4096
#define NPAD 4096

typedef unsigned int u32;
typedef unsigned short u16;
typedef unsigned long long u64;

// workspace layout (bytes)
#define OFF_R    0                  // double R[8192]          64 KB
#define OFF_CP   65536              // double CP[8][8192]     512 KB
#define OFF_CNT  589824             // int
#define OFF_CAND 589952             // u32 cand[4096]          16 KB
#define OFF_KEYS 606336             // u64 keys[4096]          32 KB
#define OFF_A16  655360             // u16 A16[8192*256]        4 MB
#define OFF_B16  (OFF_A16 + 4194304)
#define WS_REQ   (OFF_B16 + 4194304)

using f16x8 = __attribute__((ext_vector_type(8))) _Float16;
using f32x4  = __attribute__((ext_vector_type(4))) float;

#define AS1 __attribute__((address_space(1)))
#define AS3 __attribute__((address_space(3)))

__device__ __forceinline__ u16 f2h(float x) {
  union { _Float16 h; u16 u; } v;
  v.h = (_Float16)x;   // v_cvt_f16_f32, RNE
  return v.u;
}

// fallback-path init: zero R, CP, cnt (grid-stride)
__global__ void k_init(double* __restrict__ R, double* __restrict__ CP, int* __restrict__ cnt) {
  int stride = gridDim.x * blockDim.x;
  for (int i = blockIdx.x * blockDim.x + threadIdx.x; i < MD + 8 * ND; i += stride) {
    if (i < MD) R[i] = 0.0;
    else CP[i - MD] = 0.0;
  }
  if (blockIdx.x == 0 && threadIdx.x == 0) *cnt = 0;
}

// Fused: zero R/CP/cnt + convert BOTH matrices to single fp16 planes.
// R12: fp16 single-product (verified absmax 0; gemm 135 -> 65 us). c only
// feeds the cand threshold (noise 1.2e-5 << 0.26 margin) and row/col sums
// (per-term e-error 2.4e-5 averages to ~2.7e-7 on the sum); top-256
// numerators recomputed exactly in fp64 by k_score.
__global__ __launch_bounds__(256) void k_prep2(
    const float* __restrict__ A, const float* __restrict__ B,
    u16* __restrict__ A16p, u16* __restrict__ B16p,
    double* __restrict__ R, double* __restrict__ CP, int* __restrict__ cnt) {
  const int gid = blockIdx.x * 256 + threadIdx.x;
  if (gid < MD) R[gid] = 0.0;
  if (gid < 8 * ND) CP[gid] = 0.0;
  if (gid == 0) *cnt = 0;

  {
    float4 v = ((const float4*)A)[gid];
    ushort4 h;
    h.x = f2h(v.x); h.y = f2h(v.y); h.z = f2h(v.z); h.w = f2h(v.w);
    ((ushort4*)A16p)[gid] = h;
  }
  {
    float4 v = ((const float4*)B)[gid];
    ushort4 h;
    h.x = f2h(v.x); h.y = f2h(v.y); h.z = f2h(v.z); h.w = f2h(v.w);
    ((ushort4*)B16p)[gid] = h;
  }
}

// ---------------- MFMA fp16 GEMM (R15: 256x256, spill fix) -----------------
// R14 post-mortem: __launch_bounds__(512,4) = 128-reg/wave budget, but this
// geometry needs acc[8][4]=128 AGPR + fa[8]+epilogue ~= 246 regs -> massive
// scratch spill (WRITE_SIZE 20.5 MB -> 942 MB, gemm 329 us). Structure was
// CORRECT (absmax 0). R15: __launch_bounds__(512,2) -> 256-reg budget, no
// spill. Occupancy becomes reg-bound at 2 waves/SIMD (~25%) — HK-style
// config point: few waves, fat registers; per K-step each wave issues
// 32 MFMA : 12 ds_read_b128 (2.67 vs 2.0 at 128^2), and the ~1500-cy
// compute phase genuinely covers load latency for the dbuf prefetch.
// If this lands >= R13's 63 us with no spill: occupancy > ratio at this
// scale -> revert to 128^2 and attack the 8-phase schedule instead.
__global__ __launch_bounds__(512, 2) void k_gemm_mfma(
    const u16* __restrict__ A16, const u16* __restrict__ B16,
    double* __restrict__ R, double* __restrict__ CP,
    int* __restrict__ cnt, u32* __restrict__ cand, int ncap) {
  __shared__ u16 sA[2][256][32];      // 32 KB
  __shared__ u16 sB[2][256][32];      // 32 KB
  __shared__ float sRcomb[4][2][128]; // 4 KB  [wcol][wrow][i*16+quad*4+r]
  __shared__ double sCcomb[4][64];    // 2 KB  [wcol][j*16+lo]  from wrow==1

  const int tid = threadIdx.x;
  const int lane = tid & 63;
  const int wid = tid >> 6;            // 0..7
  const int wrow = wid >> 2;           // 0..1  (128-row half)
  const int wcol = wid & 3;            // 0..3  (64-col quarter)

  // XCD-aware block swizzle (1-D grid of 1024; 1024%8==0 -> bijective)
  const int g = blockIdx.x;
  const int xcd = g & 7;
  const int l = g >> 3;                // 0..127
  const int rowTile = xcd * 4 + (l & 3);   // 0..31
  const int colTile = l >> 2;              // 0..31
  const int rowBase = rowTile * 256;
  const int colBase = colTile * 256;
  double* Cmy = CP + (size_t)xcd * ND;

  const int quad = lane >> 4, lo = lane & 15;
  const int sw = (lo >> 1) & 3;
  const int cswz = (lane & 3) ^ ((lane >> 3) & 3);

  // staging: waves 0-3 -> sA 64-row quarters; waves 4-7 -> sB quarters.
  // Each wave: 4 chunks of 16 rows; per-lane row = lane>>2, col = cswz*8.
  u16* lb0;
  const u16* gbl;
  if (wid < 4) {
    lb0 = &sA[0][wid * 64][0];
    gbl = A16 + (size_t)(rowBase + wid * 64 + (lane >> 2)) * DD + cswz * 8;
  } else {
    lb0 = &sB[0][(wid - 4) * 64][0];
    gbl = B16 + (size_t)(colBase + (wid - 4) * 64 + (lane >> 2)) * DD + cswz * 8;
  }

  // Buffer stride: sA[1]-sA[0] = 256*32 = 8192 u16 (same for sB).
#define STAGE(b, kt) \
  do { \
    _Pragma("unroll") \
    for (int ch = 0; ch < 4; ++ch) { \
      const u16* gp = gbl + (size_t)(ch * 16) * DD + (kt) * 32; \
      __builtin_amdgcn_global_load_lds((const AS1 void*)gp, \
          (AS3 void*)(lb0 + (b) * 8192 + ch * 512), 16, 0, 0); \
    } \
  } while (0)

  f32x4 acc[8][4];
#pragma unroll
  for (int i = 0; i < 8; ++i)
#pragma unroll
    for (int j = 0; j < 4; ++j) acc[i][j] = (f32x4){0.f, 0.f, 0.f, 0.f};

  const int cq = (quad ^ sw) * 8;

  STAGE(0, 0);
  __syncthreads();   // drain prologue loads

#pragma unroll
  for (int kt = 0; kt < 8; ++kt) {
    const int cur = kt & 1;
    if (kt < 7) STAGE(cur ^ 1, kt + 1);   // flies under ~1500 cy of compute

    f16x8 fa[8];
#pragma unroll
    for (int t = 0; t < 8; ++t)
      fa[t] = *(const f16x8*)&sA[cur][wrow * 128 + t * 16 + lo][cq];
#pragma unroll
    for (int j = 0; j < 4; ++j) {
      f16x8 fb = *(const f16x8*)&sB[cur][wcol * 64 + j * 16 + lo][cq];
#pragma unroll
      for (int i = 0; i < 8; ++i)
        acc[i][j] = __builtin_amdgcn_mfma_f32_16x16x32_f16(fa[i], fb, acc[i][j], 0, 0, 0);
    }
    __syncthreads();
  }
#undef STAGE

  // epilogue: e = exp(2c-2); row partials fp32, col partials fp64; candidates.
  // C/D layout: col = lo, row = quad*4 + reg  (m89/m91)
  float rowp[8][4];
  double colp[4];
#pragma unroll
  for (int i = 0; i < 8; ++i)
#pragma unroll
    for (int r = 0; r < 4; ++r) rowp[i][r] = 0.f;
#pragma unroll
  for (int j = 0; j < 4; ++j) colp[j] = 0.0;

#pragma unroll
  for (int i = 0; i < 8; ++i)
#pragma unroll
    for (int j = 0; j < 4; ++j)
#pragma unroll
      for (int r = 0; r < 4; ++r) {
        float c = acc[i][j][r];
        float e = __expf(2.f * c - 2.f);
        rowp[i][r] += e;
        colp[j] += (double)e;
        if (c >= CAND_T0) {
          int row = rowBase + wrow * 128 + i * 16 + quad * 4 + r;
          int col = colBase + wcol * 64 + j * 16 + lo;
          int idx = atomicAdd(cnt, 1);
          if (idx < ncap) cand[idx] = ((u32)row << 13) | (u32)col;
        }
      }

  // row sums: reduce over lo (16 lanes) -> sum over this wave's 64 cols
#pragma unroll
  for (int i = 0; i < 8; ++i)
#pragma unroll
    for (int r = 0; r < 4; ++r) {
      float v = rowp[i][r];
#pragma unroll
      for (int off = 8; off; off >>= 1) v += __shfl_xor(v, off, 16);
      rowp[i][r] = v;
    }
  // col sums: reduce over quad -> sum over this wave's 128 rows
#pragma unroll
  for (int j = 0; j < 4; ++j) {
    double v = colp[j];
    v += __shfl_xor(v, 16);
    v += __shfl_xor(v, 32);
    colp[j] = v;
  }

  // cross-wave combine: 4 wcol partials per row, 2 wrow partials per col
  if (wcol && lo == 0) {
#pragma unroll
    for (int i = 0; i < 8; ++i)
#pragma unroll
      for (int r = 0; r < 4; ++r)
        sRcomb[wcol][wrow][i * 16 + quad * 4 + r] = rowp[i][r];
  }
  if (wrow == 1 && quad == 0) {
#pragma unroll
    for (int j = 0; j < 4; ++j) sCcomb[wcol][j * 16 + lo] = colp[j];
  }
  __syncthreads();

  if (wcol == 0 && lo == 0) {
#pragma unroll
    for (int i = 0; i < 8; ++i)
#pragma unroll
      for (int r = 0; r < 4; ++r) {
        int idx = i * 16 + quad * 4 + r;
        float tot = rowp[i][r] + sRcomb[1][wrow][idx] + sRcomb[2][wrow][idx]
                  + sRcomb[3][wrow][idx];
        atomicAdd(&R[rowBase + wrow * 128 + idx], (double)tot);
      }
  }
  if (wrow == 0 && quad == 0) {
#pragma unroll
    for (int j = 0; j < 4; ++j) {
      int idx = j * 16 + lo;
      atomicAdd(&Cmy[colBase + wcol * 64 + idx], colp[j] + sCcomb[wcol][idx]);
    }
  }
}

// ---------------- fp32 fallback GEMM (used only if ws too small) ----------------
__global__ __launch_bounds__(256) void k_gemm_f32(
    const float* __restrict__ A, const float* __restrict__ B,
    double* __restrict__ R, double* __restrict__ CP,
    int* __restrict__ cnt, u32* __restrict__ cand, int ncap) {
  __shared__ float As[32][128];
  __shared__ float Bs[32][128];
  __shared__ double colLds[16][128];
  const int tid = threadIdx.x;
  const int tx = tid & 15, ty = tid >> 4;
  const int rowBase = blockIdx.y * 128;
  const int colBase = blockIdx.x * 128;
  float acc[8][8];
#pragma unroll
  for (int i = 0; i < 8; ++i)
#pragma unroll
    for (int j = 0; j < 8; ++j) acc[i][j] = 0.f;
  const int lr = tid >> 3;
  const int lc = (tid & 7) << 2;
  for (int kk = 0; kk < DD; kk += 32) {
#pragma unroll
    for (int r = 0; r < 4; ++r) {
      int row = lr + r * 32;
      float4 av = *(const float4*)(A + (size_t)(rowBase + row) * DD + kk + lc);
      float4 bv = *(const float4*)(B + (size_t)(colBase + row) * DD + kk + lc);
      As[lc + 0][row] = av.x; As[lc + 1][row] = av.y; As[lc + 2][row] = av.z; As[lc + 3][row] = av.w;
      Bs[lc + 0][row] = bv.x; Bs[lc + 1][row] = bv.y; Bs[lc + 2][row] = bv.z; Bs[lc + 3][row] = bv.w;
    }
    __syncthreads();
#pragma unroll 4
    for (int k = 0; k < 32; ++k) {
      float a[8], b[8];
      *(float4*)(a + 0) = *(const float4*)(&As[k][ty * 8 + 0]);
      *(float4*)(a + 4) = *(const float4*)(&As[k][ty * 8 + 4]);
      *(float4*)(b + 0) = *(const float4*)(&Bs[k][tx * 8 + 0]);
      *(float4*)(b + 4) = *(const float4*)(&Bs[k][tx * 8 + 4]);
#pragma unroll
      for (int i = 0; i < 8; ++i)
#pragma unroll
        for (int j = 0; j < 8; ++j)
          acc[i][j] = fmaf(a[i], b[j], acc[i][j]);
    }
    __syncthreads();
  }
  double colpart[8];
#pragma unroll
  for (int j = 0; j < 8; ++j) colpart[j] = 0.0;
#pragma unroll
  for (int i = 0; i < 8; ++i) {
    double rp = 0.0;
#pragma unroll
    for (int j = 0; j < 8; ++j) {
      float e = __expf(2.f * acc[i][j] - 2.f);
      rp += (double)e;
      colpart[j] += (double)e;
    }
#pragma unroll
    for (int off = 8; off; off >>= 1) rp += __shfl_down(rp, off, 16);
    if (tx == 0) atomicAdd(&R[rowBase + ty * 8 + i], rp);
  }
#pragma unroll
  for (int j = 0; j < 8; ++j) colLds[ty][tx * 8 + j] = colpart[j];
  __syncthreads();
  if (tid < 128) {
    double s = 0.0;
#pragma unroll
    for (int t = 0; t < 16; ++t) s += colLds[t][tid];
    atomicAdd(&CP[colBase + tid], s);   // partition 0 only
  }
#pragma unroll
  for (int i = 0; i < 8; ++i)
#pragma unroll
    for (int j = 0; j < 8; ++j) {
      if (acc[i][j] >= CAND_T0) {
        int idx = atomicAdd(cnt, 1);
        if (idx < ncap)
          cand[idx] = ((u32)(rowBase + ty * 8 + i) << 13) | (u32)(colBase + tx * 8 + j);
      }
    }
}

// One wave per candidate: exact fp64 dot, fp64 score, orderable u64 key.
__global__ __launch_bounds__(256) void k_score(
    const float* __restrict__ A, const float* __restrict__ B,
    const double* __restrict__ R, const double* __restrict__ CP,
    const int* __restrict__ cnt, const u32* __restrict__ cand,
    u64* __restrict__ keys, int ncap) {
  int w = (int)((blockIdx.x * 256 + threadIdx.x) >> 6);
  int lane = threadIdx.x & 63;
  int n = *cnt; if (n > ncap) n = ncap;
  if (w >= n) return;
  u32 mn = cand[w];
  int m = (int)(mn >> 13), nn = (int)(mn & 8191u);
  const float* ar = A + (size_t)m * DD;
  const float* br = B + (size_t)nn * DD;
  double s = 0.0;
#pragma unroll
  for (int d = 0; d < DD; d += 64)
    s = fma((double)ar[d + lane], (double)br[d + lane], s);
#pragma unroll
  for (int off = 32; off; off >>= 1) s += __shfl_down(s, off);
  if (lane == 0) {
    double Cn = 0.0;
#pragma unroll
    for (int x = 0; x < 8; ++x) Cn += CP[(size_t)x * ND + nn];
    double sc = exp(4.0 * s - 4.0) / (R[m] * Cn);
    keys[w] = (u64)__double_as_longlong(sc);
  }
}

// (key desc, flat-idx asc) strict order; idx unique so no true ties.
__device__ __forceinline__ bool is_worse(u64 ka, u32 ma, u64 kb, u32 mb) {
  return (ka < kb) || (ka == kb && ma > mb);
}

// Single-block top-256: register/shuffle bitonic. Fast path n<=2048, with
// dynamic merge depth (np=1024 when n<=1024 -> skip one bitonic level).
// Legacy 4096 LDS bitonic fallback.
__global__ __launch_bounds__(1024) void k_sort(
    const int* __restrict__ cnt, const u32* __restrict__ cand,
    const u64* __restrict__ keys, float* __restrict__ out, int ncap) {
  __shared__ u64 sk[NPAD];
  __shared__ u32 sm[NPAD];
  const int tid = threadIdx.x;
  const int lane = tid & 63;
  const int wid = tid >> 6;
  int m = *cnt; if (m > ncap) m = ncap;

  if (m <= 2048) {
    const int NP = (m <= 1024) ? 1024 : 2048;
    const int base = wid * 128;
    const int i0 = base + lane * 2;

    // wave-local sort of each 128-segment (reg/shuffle, zero barriers).
    // Padding segments (>= NP) sort trivially and are never merged/read.
    u64 k0 = (i0 < m) ? keys[i0] : 0;
    u64 k1 = (i0 + 1 < m) ? keys[i0 + 1] : 0;
    u32 m0 = (i0 < m) ? cand[i0] : 0xFFFFFFFFu;
    u32 m1 = (i0 + 1 < m) ? cand[i0 + 1] : 0xFFFFFFFFu;
#pragma unroll
    for (int k = 2; k <= 128; k <<= 1) {
#pragma unroll
      for (int j = k >> 1; j >= 1; j >>= 1) {
        const bool bf = ((i0 & k) == 0);
        if (j == 1) {
          bool sw = bf ? is_worse(k0, m0, k1, m1) : is_worse(k1, m1, k0, m0);
          if (sw) { u64 tk = k0; k0 = k1; k1 = tk; u32 tm = m0; m0 = m1; m1 = tm; }
        } else {
          const int j2 = j >> 1;
          const bool keepb = (bf == ((lane & j2) == 0));
          u64 pk0 = __shfl_xor(k0, j2); u32 pm0 = __shfl_xor(m0, j2);
          u64 pk1 = __shfl_xor(k1, j2); u32 pm1 = __shfl_xor(m1, j2);
          if (keepb == is_worse(k0, m0, pk0, pm0)) { k0 = pk0; m0 = pm0; }
          if (keepb == is_worse(k1, m1, pk1, pm1)) { k1 = pk1; m1 = pm1; }
        }
      }
    }
    sk[i0] = k0; sk[i0 + 1] = k1; sm[i0] = m0; sm[i0 + 1] = m1;
    __syncthreads();

    for (int k = 256; k <= NP; k <<= 1) {
      for (int j = k >> 1; j >= 128; j >>= 1) {
        for (int i = tid; i < NP; i += 1024) {
          int l = i ^ j;
          if (l > i) {
            u64 ki = sk[i], kl = sk[l];
            u32 mi = sm[i], ml = sm[l];
            bool bf = ((i & k) == 0);
            bool swp = bf ? is_worse(ki, mi, kl, ml) : is_worse(kl, ml, ki, mi);
            if (swp) { sk[i] = kl; sk[l] = ki; sm[i] = ml; sm[l] = mi; }
          }
        }
        __syncthreads();
      }
      if (i0 < NP) {
        k0 = sk[i0]; k1 = sk[i0 + 1]; m0 = sm[i0]; m1 = sm[i0 + 1];
        const bool bf = ((base & k) == 0);
#pragma unroll
        for (int j = 64; j >= 2; j >>= 1) {
          const int j2 = j >> 1;
          const bool keepb = (bf == ((lane & j2) == 0));
          u64 pk0 = __shfl_xor(k0, j2); u32 pm0 = __shfl_xor(m0, j2);
          u64 pk1 = __shfl_xor(k1, j2); u32 pm1 = __shfl_xor(m1, j2);
          if (keepb == is_worse(k0, m0, pk0, pm0)) { k0 = pk0; m0 = pm0; }
          if (keepb == is_worse(k1, m1, pk1, pm1)) { k1 = pk1; m1 = pm1; }
        }
        {
          bool sw = bf ? is_worse(k0, m0, k1, m1) : is_worse(k1, m1, k0, m0);
          if (sw) { u64 tk = k0; k0 = k1; k1 = tk; u32 tm = m0; m0 = m1; m1 = tm; }
        }
      }
      __syncthreads();
      if (i0 < NP) { sk[i0] = k0; sk[i0 + 1] = k1; sm[i0] = m0; sm[i0 + 1] = m1; }
      __syncthreads();
    }
  } else {
    for (int i = tid; i < NPAD; i += 1024) { sk[i] = 0; sm[i] = 0xFFFFFFFFu; }
    __syncthreads();
    for (int i = tid; i < m; i += 1024) { sk[i] = keys[i]; sm[i] = cand[i]; }
    __syncthreads();
    for (unsigned k = 2; k <= (unsigned)NPAD; k <<= 1) {
      for (unsigned j = k >> 1; j > 0; j >>= 1) {
        for (unsigned i = tid; i < (unsigned)NPAD; i += 1024) {
          unsigned l = i ^ j;
          if (l > i) {
            u64 ki = sk[i], kl = sk[l];
            u32 mi = sm[i], ml = sm[l];
            bool dir = ((i & k) == 0);
            bool swp = dir ? is_worse(ki, mi, kl, ml) : is_worse(kl, ml, ki, mi);
            if (swp) { sk[i] = kl; sk[l] = ki; sm[i] = ml; sm[l] = mi; }
          }
        }
        __syncthreads();
      }
    }
  }

  for (int r = tid; r < KTOP; r += 1024) {
    u32 mn = sm[r];
    u64 kk = sk[r];
    out[r] = (float)(mn >> 13);
    out[KTOP + r] = (float)(mn & 8191u);
    out[2 * KTOP + r] = (float)__longlong_as_double((long long)kk);
  }
}

extern "C" void kernel_launch(void* const* d_in, const int* in_sizes, int n_in,
                              void* d_out, int out_size, void* d_ws, size_t ws_size,
                              hipStream_t stream) {
  (void)in_sizes; (void)n_in; (void)out_size;
  const float* A = (const float*)d_in[0];  // ref_feats [8192,256]
  const float* B = (const float*)d_in[1];  // src_feats [8192,256]
  float* out = (float*)d_out;
  char* ws = (char*)d_ws;
  double* R = (double*)(ws + OFF_R);
  double* CP = (double*)(ws + OFF_CP);
  int* cnt = (int*)(ws + OFF_CNT);
  u32* cand = (u32*)(ws + OFF_CAND);
  u64* keys = (u64*)(ws + OFF_KEYS);

  if (ws_size >= (size_t)WS_REQ) {
    u16* A16p = (u16*)(ws + OFF_A16);
    u16* B16p = (u16*)(ws + OFF_B16);
    hipLaunchKernelGGL(k_prep2, dim3(2048), dim3(256), 0, stream,
                       A, B, A16p, B16p, R, CP, cnt);
    hipLaunchKernelGGL(k_gemm_mfma, dim3(1024), dim3(512), 0, stream,
                       A16p, B16p, R, CP, cnt, cand, NCAP);
  } else {
    hipLaunchKernelGGL(k_init, dim3(288), dim3(256), 0, stream, R, CP, cnt);
    hipLaunchKernelGGL(k_gemm_f32, dim3(ND / 128, MD / 128), dim3(256), 0, stream,
                       A, B, R, CP, cnt, cand, NCAP);
  }

  hipLaunchKernelGGL(k_score, dim3(NCAP / 4), dim3(256), 0, stream,
                     A, B, R, CP, cnt, cand, keys, NCAP);
  hipLaunchKernelGGL(k_sort, dim3(1), dim3(1024), 0, stream,
                     cnt, cand, keys, out, NCAP);
}

// Round 5
// 150.460 us; speedup vs baseline: 2.5673x; 1.0047x over previous
//
#include <hip/hip_runtime.h>

#define MD 8192
#define ND 8192
#define DD 256
#define KTOP 256
#define CAND_T0 0.26f
#define NCAP 4096
#define NPAD 4096

typedef unsigned int u32;
typedef unsigned short u16;
typedef unsigned long long u64;

// workspace layout (bytes)
#define OFF_R    0                  // double R[8192]          64 KB
#define OFF_CP   65536              // double CP[8][8192]     512 KB
#define OFF_CNT  589824             // int
#define OFF_CAND 589952             // u32 cand[4096]          16 KB
#define OFF_KEYS 606336             // u64 keys[4096]          32 KB
#define OFF_A16  655360             // u16 A16[8192*256]        4 MB
#define OFF_B16  (OFF_A16 + 4194304)
#define WS_REQ   (OFF_B16 + 4194304)

using f16x8 = __attribute__((ext_vector_type(8))) _Float16;
using f32x4  = __attribute__((ext_vector_type(4))) float;

#define AS1 __attribute__((address_space(1)))
#define AS3 __attribute__((address_space(3)))

__device__ __forceinline__ u16 f2h(float x) {
  union { _Float16 h; u16 u; } v;
  v.h = (_Float16)x;   // v_cvt_f16_f32, RNE
  return v.u;
}

// fallback-path init: zero R, CP, cnt (grid-stride)
__global__ void k_init(double* __restrict__ R, double* __restrict__ CP, int* __restrict__ cnt) {
  int stride = gridDim.x * blockDim.x;
  for (int i = blockIdx.x * blockDim.x + threadIdx.x; i < MD + 8 * ND; i += stride) {
    if (i < MD) R[i] = 0.0;
    else CP[i - MD] = 0.0;
  }
  if (blockIdx.x == 0 && threadIdx.x == 0) *cnt = 0;
}

// Fused: zero R/CP/cnt + convert BOTH matrices to single fp16 planes.
// R12: fp16 single-product (verified absmax 0). c only feeds the cand
// threshold (noise 1.2e-5 << 0.26 margin) and row/col sums; top-256
// numerators recomputed exactly in fp64 by k_score.
__global__ __launch_bounds__(256) void k_prep2(
    const float* __restrict__ A, const float* __restrict__ B,
    u16* __restrict__ A16p, u16* __restrict__ B16p,
    double* __restrict__ R, double* __restrict__ CP, int* __restrict__ cnt) {
  const int gid = blockIdx.x * 256 + threadIdx.x;
  if (gid < MD) R[gid] = 0.0;
  if (gid < 8 * ND) CP[gid] = 0.0;
  if (gid == 0) *cnt = 0;

  {
    float4 v = ((const float4*)A)[gid];
    ushort4 h;
    h.x = f2h(v.x); h.y = f2h(v.y); h.z = f2h(v.z); h.w = f2h(v.w);
    ((ushort4*)A16p)[gid] = h;
  }
  {
    float4 v = ((const float4*)B)[gid];
    ushort4 h;
    h.x = f2h(v.x); h.y = f2h(v.y); h.z = f2h(v.z); h.w = f2h(v.w);
    ((ushort4*)B16p)[gid] = h;
  }
}

// ---------------- MFMA fp16 GEMM (R16: 256x256, 4-phase interleave) --------
// R15 post-mortem: 2-phase at 1 block/CU serializes read-burst/MFMA-burst/
// barrier (77 us). R16 ports the HK-style phase schedule (T2+T3+T5):
//  - BK=64, 4 K-tiles, LDS 128 KB dbuf (1 block/CU by design, like HK 256^2).
//  - row-XOR swizzle byte^=((row&7)<<4) on BOTH sides (rule #21): linear
//    gload_lds dest + inverse-permuted per-lane GLOBAL source
//    (gcol=((lane&7)^(lane>>3))*8) + same XOR on every ds_read. At BK=64
//    the 128B row stride is bank-0-everywhere without it.
//  - per K-tile 4 phases: {ds_read quadrant, 2 staging loads for kt+1,
//    s_barrier, setprio(1), 16 MFMA, setprio(0), s_barrier}. A-frags held
//    live across phases (reads/phase 12/8/4/0). Tile boundary: vmcnt(0)
//    (loads had ~3 phases to land) + __syncthreads.
// Regs: fa 64 + fb 32 + acc 128 AGPR + misc ~= 245 <= 256 budget, no spill
// (watch WRITE_SIZE; R14's spill signature was 942 MB).
__global__ __launch_bounds__(512, 2) void k_gemm_mfma(
    const u16* __restrict__ A16, const u16* __restrict__ B16,
    double* __restrict__ R, double* __restrict__ CP,
    int* __restrict__ cnt, u32* __restrict__ cand, int ncap) {
  __shared__ u16 sA[2][256][64];      // 64 KB
  __shared__ u16 sB[2][256][64];      // 64 KB
  __shared__ float sRcomb[4][2][128]; // 4 KB  [wcol][wrow][i*16+quad*4+r]
  __shared__ double sCcomb[4][64];    // 2 KB  [wcol][j*16+lo]  from wrow==1

  const int tid = threadIdx.x;
  const int lane = tid & 63;
  const int wid = tid >> 6;            // 0..7
  const int wrow = wid >> 2;           // 0..1  (128-row half)
  const int wcol = wid & 3;            // 0..3  (64-col quarter)

  // XCD-aware block swizzle (1-D grid of 1024; 1024%8==0 -> bijective)
  const int g = blockIdx.x;
  const int xcd = g & 7;
  const int l = g >> 3;                // 0..127
  const int rowTile = xcd * 4 + (l & 3);   // 0..31
  const int colTile = l >> 2;              // 0..31
  const int rowBase = rowTile * 256;
  const int colBase = colTile * 256;
  double* Cmy = CP + (size_t)xcd * ND;

  const int quad = lane >> 4, lo = lane & 15;

  // per-lane staging source bases (inverse-swizzled global col):
  // round q covers rows q*64 + wid*8 + (lane>>3); col = ((lane&7)^(lane>>3))*8
  const int srow = wid * 8 + (lane >> 3);
  const int scol = ((lane & 7) ^ (lane >> 3)) * 8;
  const u16* gA = A16 + (size_t)(rowBase + srow) * DD + scol;
  const u16* gB = B16 + (size_t)(colBase + srow) * DD + scol;

  // STAGE round q (0..3 = A rounds, 4..7 = B rounds) for K-tile ktn into buf nb.
  // LDS dest linear: buf base + q*8192 B + wid*1024 B (+ lane*16 by HW).
#define STAGE_A(nb, ktn, q) \
  __builtin_amdgcn_global_load_lds( \
      (const AS1 void*)(gA + (size_t)((q) * 64) * DD + (ktn) * 64), \
      (AS3 void*)(&sA[nb][0][0] + (q) * 4096 + wid * 512), 16, 0, 0)
#define STAGE_B(nb, ktn, q) \
  __builtin_amdgcn_global_load_lds( \
      (const AS1 void*)(gB + (size_t)((q) * 64) * DD + (ktn) * 64), \
      (AS3 void*)(&sB[nb][0][0] + (q) * 4096 + wid * 512), 16, 0, 0)

  // swizzled fragment read: row-major [256][64], 16B at (row, ks*32+quad*8)
#define LDFRAG(buf, row, ks) \
  (*(const f16x8*)&(buf)[(size_t)(row) * 64 + \
      ((((ks) * 32 + quad * 8)) ^ (((row) & 7) * 8))])

  f32x4 acc[8][4];
#pragma unroll
  for (int i = 0; i < 8; ++i)
#pragma unroll
    for (int j = 0; j < 4; ++j) acc[i][j] = (f32x4){0.f, 0.f, 0.f, 0.f};

  // prologue: stage K-tile 0 into buf 0, full drain
#pragma unroll
  for (int q = 0; q < 4; ++q) { STAGE_A(0, 0, q); STAGE_B(0, 0, q); }
  __syncthreads();

#pragma unroll
  for (int kt = 0; kt < 4; ++kt) {
    const int cur = kt & 1;
    const int nb = cur ^ 1;
    const u16* a0 = &sA[cur][0][0];
    const u16* b0 = &sB[cur][0][0];
    f16x8 fa[8][2], fb[4][2];

    // ---- phase 0: A m0-3 + B n0-1 reads; stage A rounds 0-1; MFMA m0-3 x n0-1
#pragma unroll
    for (int m = 0; m < 4; ++m)
#pragma unroll
      for (int ks = 0; ks < 2; ++ks)
        fa[m][ks] = LDFRAG(a0, wrow * 128 + m * 16 + lo, ks);
#pragma unroll
    for (int n = 0; n < 2; ++n)
#pragma unroll
      for (int ks = 0; ks < 2; ++ks)
        fb[n][ks] = LDFRAG(b0, wcol * 64 + n * 16 + lo, ks);
    if (kt < 3) { STAGE_A(nb, kt + 1, 0); STAGE_A(nb, kt + 1, 1); }
    __builtin_amdgcn_s_barrier();
    __builtin_amdgcn_s_setprio(1);
#pragma unroll
    for (int ks = 0; ks < 2; ++ks)
#pragma unroll
      for (int n = 0; n < 2; ++n)
#pragma unroll
        for (int m = 0; m < 4; ++m)
          acc[m][n] = __builtin_amdgcn_mfma_f32_16x16x32_f16(fa[m][ks], fb[n][ks], acc[m][n], 0, 0, 0);
    __builtin_amdgcn_s_setprio(0);
    __builtin_amdgcn_s_barrier();

    // ---- phase 1: A m4-7 reads; stage A rounds 2-3; MFMA m4-7 x n0-1
#pragma unroll
    for (int m = 4; m < 8; ++m)
#pragma unroll
      for (int ks = 0; ks < 2; ++ks)
        fa[m][ks] = LDFRAG(a0, wrow * 128 + m * 16 + lo, ks);
    if (kt < 3) { STAGE_A(nb, kt + 1, 2); STAGE_A(nb, kt + 1, 3); }
    __builtin_amdgcn_s_barrier();
    __builtin_amdgcn_s_setprio(1);
#pragma unroll
    for (int ks = 0; ks < 2; ++ks)
#pragma unroll
      for (int n = 0; n < 2; ++n)
#pragma unroll
        for (int m = 4; m < 8; ++m)
          acc[m][n] = __builtin_amdgcn_mfma_f32_16x16x32_f16(fa[m][ks], fb[n][ks], acc[m][n], 0, 0, 0);
    __builtin_amdgcn_s_setprio(0);
    __builtin_amdgcn_s_barrier();

    // ---- phase 2: B n2-3 reads; stage B rounds 0-1; MFMA m0-3 x n2-3
#pragma unroll
    for (int n = 2; n < 4; ++n)
#pragma unroll
      for (int ks = 0; ks < 2; ++ks)
        fb[n][ks] = LDFRAG(b0, wcol * 64 + n * 16 + lo, ks);
    if (kt < 3) { STAGE_B(nb, kt + 1, 0); STAGE_B(nb, kt + 1, 1); }
    __builtin_amdgcn_s_barrier();
    __builtin_amdgcn_s_setprio(1);
#pragma unroll
    for (int ks = 0; ks < 2; ++ks)
#pragma unroll
      for (int n = 2; n < 4; ++n)
#pragma unroll
        for (int m = 0; m < 4; ++m)
          acc[m][n] = __builtin_amdgcn_mfma_f32_16x16x32_f16(fa[m][ks], fb[n][ks], acc[m][n], 0, 0, 0);
    __builtin_amdgcn_s_setprio(0);
    __builtin_amdgcn_s_barrier();

    // ---- phase 3: stage B rounds 2-3; MFMA m4-7 x n2-3
    if (kt < 3) { STAGE_B(nb, kt + 1, 2); STAGE_B(nb, kt + 1, 3); }
    __builtin_amdgcn_s_barrier();
    __builtin_amdgcn_s_setprio(1);
#pragma unroll
    for (int ks = 0; ks < 2; ++ks)
#pragma unroll
      for (int n = 2; n < 4; ++n)
#pragma unroll
        for (int m = 4; m < 8; ++m)
          acc[m][n] = __builtin_amdgcn_mfma_f32_16x16x32_f16(fa[m][ks], fb[n][ks], acc[m][n], 0, 0, 0);
    __builtin_amdgcn_s_setprio(0);

    // ---- tile boundary: next buffer's 8 staging loads must have landed
    if (kt < 3) asm volatile("s_waitcnt vmcnt(0)" ::: "memory");
    __syncthreads();
  }
#undef STAGE_A
#undef STAGE_B
#undef LDFRAG

  // epilogue: e = exp(2c-2); row partials fp32, col partials fp64; candidates.
  // C/D layout: col = lo, row = quad*4 + reg  (m89/m91)
  float rowp[8][4];
  double colp[4];
#pragma unroll
  for (int i = 0; i < 8; ++i)
#pragma unroll
    for (int r = 0; r < 4; ++r) rowp[i][r] = 0.f;
#pragma unroll
  for (int j = 0; j < 4; ++j) colp[j] = 0.0;

#pragma unroll
  for (int i = 0; i < 8; ++i)
#pragma unroll
    for (int j = 0; j < 4; ++j)
#pragma unroll
      for (int r = 0; r < 4; ++r) {
        float c = acc[i][j][r];
        float e = __expf(2.f * c - 2.f);
        rowp[i][r] += e;
        colp[j] += (double)e;
        if (c >= CAND_T0) {
          int row = rowBase + wrow * 128 + i * 16 + quad * 4 + r;
          int col = colBase + wcol * 64 + j * 16 + lo;
          int idx = atomicAdd(cnt, 1);
          if (idx < ncap) cand[idx] = ((u32)row << 13) | (u32)col;
        }
      }

  // row sums: reduce over lo (16 lanes) -> sum over this wave's 64 cols
#pragma unroll
  for (int i = 0; i < 8; ++i)
#pragma unroll
    for (int r = 0; r < 4; ++r) {
      float v = rowp[i][r];
#pragma unroll
      for (int off = 8; off; off >>= 1) v += __shfl_xor(v, off, 16);
      rowp[i][r] = v;
    }
  // col sums: reduce over quad -> sum over this wave's 128 rows
#pragma unroll
  for (int j = 0; j < 4; ++j) {
    double v = colp[j];
    v += __shfl_xor(v, 16);
    v += __shfl_xor(v, 32);
    colp[j] = v;
  }

  // cross-wave combine: 4 wcol partials per row, 2 wrow partials per col
  if (wcol && lo == 0) {
#pragma unroll
    for (int i = 0; i < 8; ++i)
#pragma unroll
      for (int r = 0; r < 4; ++r)
        sRcomb[wcol][wrow][i * 16 + quad * 4 + r] = rowp[i][r];
  }
  if (wrow == 1 && quad == 0) {
#pragma unroll
    for (int j = 0; j < 4; ++j) sCcomb[wcol][j * 16 + lo] = colp[j];
  }
  __syncthreads();

  if (wcol == 0 && lo == 0) {
#pragma unroll
    for (int i = 0; i < 8; ++i)
#pragma unroll
      for (int r = 0; r < 4; ++r) {
        int idx = i * 16 + quad * 4 + r;
        float tot = rowp[i][r] + sRcomb[1][wrow][idx] + sRcomb[2][wrow][idx]
                  + sRcomb[3][wrow][idx];
        atomicAdd(&R[rowBase + wrow * 128 + idx], (double)tot);
      }
  }
  if (wrow == 0 && quad == 0) {
#pragma unroll
    for (int j = 0; j < 4; ++j) {
      int idx = j * 16 + lo;
      atomicAdd(&Cmy[colBase + wcol * 64 + idx], colp[j] + sCcomb[wcol][idx]);
    }
  }
}

// ---------------- fp32 fallback GEMM (used only if ws too small) ----------------
__global__ __launch_bounds__(256) void k_gemm_f32(
    const float* __restrict__ A, const float* __restrict__ B,
    double* __restrict__ R, double* __restrict__ CP,
    int* __restrict__ cnt, u32* __restrict__ cand, int ncap) {
  __shared__ float As[32][128];
  __shared__ float Bs[32][128];
  __shared__ double colLds[16][128];
  const int tid = threadIdx.x;
  const int tx = tid & 15, ty = tid >> 4;
  const int rowBase = blockIdx.y * 128;
  const int colBase = blockIdx.x * 128;
  float acc[8][8];
#pragma unroll
  for (int i = 0; i < 8; ++i)
#pragma unroll
    for (int j = 0; j < 8; ++j) acc[i][j] = 0.f;
  const int lr = tid >> 3;
  const int lc = (tid & 7) << 2;
  for (int kk = 0; kk < DD; kk += 32) {
#pragma unroll
    for (int r = 0; r < 4; ++r) {
      int row = lr + r * 32;
      float4 av = *(const float4*)(A + (size_t)(rowBase + row) * DD + kk + lc);
      float4 bv = *(const float4*)(B + (size_t)(colBase + row) * DD + kk + lc);
      As[lc + 0][row] = av.x; As[lc + 1][row] = av.y; As[lc + 2][row] = av.z; As[lc + 3][row] = av.w;
      Bs[lc + 0][row] = bv.x; Bs[lc + 1][row] = bv.y; Bs[lc + 2][row] = bv.z; Bs[lc + 3][row] = bv.w;
    }
    __syncthreads();
#pragma unroll 4
    for (int k = 0; k < 32; ++k) {
      float a[8], b[8];
      *(float4*)(a + 0) = *(const float4*)(&As[k][ty * 8 + 0]);
      *(float4*)(a + 4) = *(const float4*)(&As[k][ty * 8 + 4]);
      *(float4*)(b + 0) = *(const float4*)(&Bs[k][tx * 8 + 0]);
      *(float4*)(b + 4) = *(const float4*)(&Bs[k][tx * 8 + 4]);
#pragma unroll
      for (int i = 0; i < 8; ++i)
#pragma unroll
        for (int j = 0; j < 8; ++j)
          acc[i][j] = fmaf(a[i], b[j], acc[i][j]);
    }
    __syncthreads();
  }
  double colpart[8];
#pragma unroll
  for (int j = 0; j < 8; ++j) colpart[j] = 0.0;
#pragma unroll
  for (int i = 0; i < 8; ++i) {
    double rp = 0.0;
#pragma unroll
    for (int j = 0; j < 8; ++j) {
      float e = __expf(2.f * acc[i][j] - 2.f);
      rp += (double)e;
      colpart[j] += (double)e;
    }
#pragma unroll
    for (int off = 8; off; off >>= 1) rp += __shfl_down(rp, off, 16);
    if (tx == 0) atomicAdd(&R[rowBase + ty * 8 + i], rp);
  }
#pragma unroll
  for (int j = 0; j < 8; ++j) colLds[ty][tx * 8 + j] = colpart[j];
  __syncthreads();
  if (tid < 128) {
    double s = 0.0;
#pragma unroll
    for (int t = 0; t < 16; ++t) s += colLds[t][tid];
    atomicAdd(&CP[colBase + tid], s);   // partition 0 only
  }
#pragma unroll
  for (int i = 0; i < 8; ++i)
#pragma unroll
    for (int j = 0; j < 8; ++j) {
      if (acc[i][j] >= CAND_T0) {
        int idx = atomicAdd(cnt, 1);
        if (idx < ncap)
          cand[idx] = ((u32)(rowBase + ty * 8 + i) << 13) | (u32)(colBase + tx * 8 + j);
      }
    }
}

// One wave per candidate: exact fp64 dot, fp64 score, orderable u64 key.
__global__ __launch_bounds__(256) void k_score(
    const float* __restrict__ A, const float* __restrict__ B,
    const double* __restrict__ R, const double* __restrict__ CP,
    const int* __restrict__ cnt, const u32* __restrict__ cand,
    u64* __restrict__ keys, int ncap) {
  int w = (int)((blockIdx.x * 256 + threadIdx.x) >> 6);
  int lane = threadIdx.x & 63;
  int n = *cnt; if (n > ncap) n = ncap;
  if (w >= n) return;
  u32 mn = cand[w];
  int m = (int)(mn >> 13), nn = (int)(mn & 8191u);
  const float* ar = A + (size_t)m * DD;
  const float* br = B + (size_t)nn * DD;
  double s = 0.0;
#pragma unroll
  for (int d = 0; d < DD; d += 64)
    s = fma((double)ar[d + lane], (double)br[d + lane], s);
#pragma unroll
  for (int off = 32; off; off >>= 1) s += __shfl_down(s, off);
  if (lane == 0) {
    double Cn = 0.0;
#pragma unroll
    for (int x = 0; x < 8; ++x) Cn += CP[(size_t)x * ND + nn];
    double sc = exp(4.0 * s - 4.0) / (R[m] * Cn);
    keys[w] = (u64)__double_as_longlong(sc);
  }
}

// (key desc, flat-idx asc) strict order; idx unique so no true ties.
__device__ __forceinline__ bool is_worse(u64 ka, u32 ma, u64 kb, u32 mb) {
  return (ka < kb) || (ka == kb && ma > mb);
}

// Single-block top-256: register/shuffle bitonic. Fast path n<=2048, with
// dynamic merge depth (np=1024 when n<=1024 -> skip one bitonic level).
// Legacy 4096 LDS bitonic fallback.
__global__ __launch_bounds__(1024) void k_sort(
    const int* __restrict__ cnt, const u32* __restrict__ cand,
    const u64* __restrict__ keys, float* __restrict__ out, int ncap) {
  __shared__ u64 sk[NPAD];
  __shared__ u32 sm[NPAD];
  const int tid = threadIdx.x;
  const int lane = tid & 63;
  const int wid = tid >> 6;
  int m = *cnt; if (m > ncap) m = ncap;

  if (m <= 2048) {
    const int NP = (m <= 1024) ? 1024 : 2048;
    const int base = wid * 128;
    const int i0 = base + lane * 2;

    // wave-local sort of each 128-segment (reg/shuffle, zero barriers).
    // Padding segments (>= NP) sort trivially and are never merged/read.
    u64 k0 = (i0 < m) ? keys[i0] : 0;
    u64 k1 = (i0 + 1 < m) ? keys[i0 + 1] : 0;
    u32 m0 = (i0 < m) ? cand[i0] : 0xFFFFFFFFu;
    u32 m1 = (i0 + 1 < m) ? cand[i0 + 1] : 0xFFFFFFFFu;
#pragma unroll
    for (int k = 2; k <= 128; k <<= 1) {
#pragma unroll
      for (int j = k >> 1; j >= 1; j >>= 1) {
        const bool bf = ((i0 & k) == 0);
        if (j == 1) {
          bool sw = bf ? is_worse(k0, m0, k1, m1) : is_worse(k1, m1, k0, m0);
          if (sw) { u64 tk = k0; k0 = k1; k1 = tk; u32 tm = m0; m0 = m1; m1 = tm; }
        } else {
          const int j2 = j >> 1;
          const bool keepb = (bf == ((lane & j2) == 0));
          u64 pk0 = __shfl_xor(k0, j2); u32 pm0 = __shfl_xor(m0, j2);
          u64 pk1 = __shfl_xor(k1, j2); u32 pm1 = __shfl_xor(m1, j2);
          if (keepb == is_worse(k0, m0, pk0, pm0)) { k0 = pk0; m0 = pm0; }
          if (keepb == is_worse(k1, m1, pk1, pm1)) { k1 = pk1; m1 = pm1; }
        }
      }
    }
    sk[i0] = k0; sk[i0 + 1] = k1; sm[i0] = m0; sm[i0 + 1] = m1;
    __syncthreads();

    for (int k = 256; k <= NP; k <<= 1) {
      for (int j = k >> 1; j >= 128; j >>= 1) {
        for (int i = tid; i < NP; i += 1024) {
          int l = i ^ j;
          if (l > i) {
            u64 ki = sk[i], kl = sk[l];
            u32 mi = sm[i], ml = sm[l];
            bool bf = ((i & k) == 0);
            bool swp = bf ? is_worse(ki, mi, kl, ml) : is_worse(kl, ml, ki, mi);
            if (swp) { sk[i] = kl; sk[l] = ki; sm[i] = ml; sm[l] = mi; }
          }
        }
        __syncthreads();
      }
      if (i0 < NP) {
        k0 = sk[i0]; k1 = sk[i0 + 1]; m0 = sm[i0]; m1 = sm[i0 + 1];
        const bool bf = ((base & k) == 0);
#pragma unroll
        for (int j = 64; j >= 2; j >>= 1) {
          const int j2 = j >> 1;
          const bool keepb = (bf == ((lane & j2) == 0));
          u64 pk0 = __shfl_xor(k0, j2); u32 pm0 = __shfl_xor(m0, j2);
          u64 pk1 = __shfl_xor(k1, j2); u32 pm1 = __shfl_xor(m1, j2);
          if (keepb == is_worse(k0, m0, pk0, pm0)) { k0 = pk0; m0 = pm0; }
          if (keepb == is_worse(k1, m1, pk1, pm1)) { k1 = pk1; m1 = pm1; }
        }
        {
          bool sw = bf ? is_worse(k0, m0, k1, m1) : is_worse(k1, m1, k0, m0);
          if (sw) { u64 tk = k0; k0 = k1; k1 = tk; u32 tm = m0; m0 = m1; m1 = tm; }
        }
      }
      __syncthreads();
      if (i0 < NP) { sk[i0] = k0; sk[i0 + 1] = k1; sm[i0] = m0; sm[i0 + 1] = m1; }
      __syncthreads();
    }
  } else {
    for (int i = tid; i < NPAD; i += 1024) { sk[i] = 0; sm[i] = 0xFFFFFFFFu; }
    __syncthreads();
    for (int i = tid; i < m; i += 1024) { sk[i] = keys[i]; sm[i] = cand[i]; }
    __syncthreads();
    for (unsigned k = 2; k <= (unsigned)NPAD; k <<= 1) {
      for (unsigned j = k >> 1; j > 0; j >>= 1) {
        for (unsigned i = tid; i < (unsigned)NPAD; i += 1024) {
          unsigned l = i ^ j;
          if (l > i) {
            u64 ki = sk[i], kl = sk[l];
            u32 mi = sm[i], ml = sm[l];
            bool dir = ((i & k) == 0);
            bool swp = dir ? is_worse(ki, mi, kl, ml) : is_worse(kl, ml, ki, mi);
            if (swp) { sk[i] = kl; sk[l] = ki; sm[i] = ml; sm[l] = mi; }
          }
        }
        __syncthreads();
      }
    }
  }

  for (int r = tid; r < KTOP; r += 1024) {
    u32 mn = sm[r];
    u64 kk = sk[r];
    out[r] = (float)(mn >> 13);
    out[KTOP + r] = (float)(mn & 8191u);
    out[2 * KTOP + r] = (float)__longlong_as_double((long long)kk);
  }
}

extern "C" void kernel_launch(void* const* d_in, const int* in_sizes, int n_in,
                              void* d_out, int out_size, void* d_ws, size_t ws_size,
                              hipStream_t stream) {
  (void)in_sizes; (void)n_in; (void)out_size;
  const float* A = (const float*)d_in[0];  // ref_feats [8192,256]
  const float* B = (const float*)d_in[1];  // src_feats [8192,256]
  float* out = (float*)d_out;
  char* ws = (char*)d_ws;
  double* R = (double*)(ws + OFF_R);
  double* CP = (double*)(ws + OFF_CP);
  int* cnt = (int*)(ws + OFF_CNT);
  u32* cand = (u32*)(ws + OFF_CAND);
  u64* keys = (u64*)(ws + OFF_KEYS);

  if (ws_size >= (size_t)WS_REQ) {
    u16* A16p = (u16*)(ws + OFF_A16);
    u16* B16p = (u16*)(ws + OFF_B16);
    hipLaunchKernelGGL(k_prep2, dim3(2048), dim3(256), 0, stream,
                       A, B, A16p, B16p, R, CP, cnt);
    hipLaunchKernelGGL(k_gemm_mfma, dim3(1024), dim3(512), 0, stream,
                       A16p, B16p, R, CP, cnt, cand, NCAP);
  } else {
    hipLaunchKernelGGL(k_init, dim3(288), dim3(256), 0, stream, R, CP, cnt);
    hipLaunchKernelGGL(k_gemm_f32, dim3(ND / 128, MD / 128), dim3(256), 0, stream,
                       A, B, R, CP, cnt, cand, NCAP);
  }

  hipLaunchKernelGGL(k_score, dim3(NCAP / 4), dim3(256), 0, stream,
                     A, B, R, CP, cnt, cand, keys, NCAP);
  hipLaunchKernelGGL(k_sort, dim3(1), dim3(1024), 0, stream,
                     cnt, cand, keys, out, NCAP);
}

// Round 6
// 149.432 us; speedup vs baseline: 2.5850x; 1.0069x over previous
//
#include <hip/hip_runtime.h>

#define MD 8192
#define ND 8192
#define DD 256
#define KTOP 256
#define CAND_T0 0.26f
#define NCAP 4096
#define NPAD 4096

typedef unsigned int u32;
typedef unsigned short u16;
typedef unsigned long long u64;

// workspace layout (bytes)
#define OFF_R    0                  // double R[8192]          64 KB
#define OFF_CP   65536              // double CP[8][8192]     512 KB
#define OFF_CNT  589824             // int
#define OFF_CAND 589952             // u32 cand[4096]          16 KB
#define OFF_KEYS 606336             // u64 keys[4096]          32 KB
#define OFF_A16  655360             // u16 A16[8192*256]        4 MB
#define OFF_B16  (OFF_A16 + 4194304)
#define WS_REQ   (OFF_B16 + 4194304)

using f16x8 = __attribute__((ext_vector_type(8))) _Float16;
using f32x4  = __attribute__((ext_vector_type(4))) float;

#define AS1 __attribute__((address_space(1)))
#define AS3 __attribute__((address_space(3)))

__device__ __forceinline__ u16 f2h(float x) {
  union { _Float16 h; u16 u; } v;
  v.h = (_Float16)x;   // v_cvt_f16_f32, RNE
  return v.u;
}

// fallback-path init: zero R, CP, cnt (grid-stride)
__global__ void k_init(double* __restrict__ R, double* __restrict__ CP, int* __restrict__ cnt) {
  int stride = gridDim.x * blockDim.x;
  for (int i = blockIdx.x * blockDim.x + threadIdx.x; i < MD + 8 * ND; i += stride) {
    if (i < MD) R[i] = 0.0;
    else CP[i - MD] = 0.0;
  }
  if (blockIdx.x == 0 && threadIdx.x == 0) *cnt = 0;
}

// Fused: zero R/CP/cnt + convert BOTH matrices to single fp16 planes.
// R12: fp16 single-product (verified absmax 0). c only feeds the cand
// threshold (noise 1.2e-5 << 0.26 margin) and row/col sums; top-256
// numerators recomputed exactly in fp64 by k_score.
__global__ __launch_bounds__(256) void k_prep2(
    const float* __restrict__ A, const float* __restrict__ B,
    u16* __restrict__ A16p, u16* __restrict__ B16p,
    double* __restrict__ R, double* __restrict__ CP, int* __restrict__ cnt) {
  const int gid = blockIdx.x * 256 + threadIdx.x;
  if (gid < MD) R[gid] = 0.0;
  if (gid < 8 * ND) CP[gid] = 0.0;
  if (gid == 0) *cnt = 0;

  {
    float4 v = ((const float4*)A)[gid];
    ushort4 h;
    h.x = f2h(v.x); h.y = f2h(v.y); h.z = f2h(v.z); h.w = f2h(v.w);
    ((ushort4*)A16p)[gid] = h;
  }
  {
    float4 v = ((const float4*)B)[gid];
    ushort4 h;
    h.x = f2h(v.x); h.y = f2h(v.y); h.z = f2h(v.z); h.w = f2h(v.w);
    ((ushort4*)B16p)[gid] = h;
  }
}

// ---------------- MFMA fp16 GEMM (R17: 8-phase counted-vmcnt pipeline) -----
// R16 post-mortem: 4-phase skeleton + vmcnt(0) drain per K-tile = "8-phase-
// with-drain0 == 1-phase" (m218). R17 ports T3+T4 faithfully:
//  - half-tile staging stream (1 half = 128x64 = 2 gload_lds/thread/phase),
//    lag-2 targeting: A-halves in phases 3,4/7,8; odd-tile B-halves in
//    phases 1,2 of the NEXT iteration. Every stage target's last reader
//    passed a barrier before the stage issues (hazard-checked per phase).
//  - counted vmcnt(4) at phases 4 and 8 ONLY (loads issued >=4 phases ago);
//    vmcnt(0) only at last iteration's phase 4. Prologue stages T0+T1,
//    waits vmcnt(8) (T1 stays in flight).
//  - sched_barrier(0) at phase start pins stages below the preceding
//    barrier (cross-wave overwrite hazard); "memory" waitcnt asm keeps
//    the in-order vmcnt counting valid (m135).
// Geometry/swizzle/epilogue identical to R16 (verified: absmax 0, 0 bank
// conflicts). Spill tripwire: WRITE_SIZE must stay ~10 MB.
__global__ __launch_bounds__(512, 2) void k_gemm_mfma(
    const u16* __restrict__ A16, const u16* __restrict__ B16,
    double* __restrict__ R, double* __restrict__ CP,
    int* __restrict__ cnt, u32* __restrict__ cand, int ncap) {
  __shared__ u16 sA[2][256][64];      // 64 KB
  __shared__ u16 sB[2][256][64];      // 64 KB
  __shared__ float sRcomb[4][2][128]; // 4 KB
  __shared__ double sCcomb[4][64];    // 2 KB

  const int tid = threadIdx.x;
  const int lane = tid & 63;
  const int wid = tid >> 6;            // 0..7
  const int wrow = wid >> 2;           // 0..1  (128-row half)
  const int wcol = wid & 3;            // 0..3  (64-col quarter)

  // XCD-aware block swizzle (1-D grid of 1024; 1024%8==0 -> bijective)
  const int g = blockIdx.x;
  const int xcd = g & 7;
  const int l = g >> 3;
  const int rowTile = xcd * 4 + (l & 3);
  const int colTile = l >> 2;
  const int rowBase = rowTile * 256;
  const int colBase = colTile * 256;
  double* Cmy = CP + (size_t)xcd * ND;

  const int quad = lane >> 4, lo = lane & 15;

  // staging: round = 64 rows staged by all 512 threads (8 KB). Thread t:
  // row-in-round = t>>3, global col inverse-swizzled ((t&7)^(row&7))*8.
  const int srow = tid >> 3;                       // 0..63
  const int scol = ((tid & 7) ^ (srow & 7)) * 8;
  const u16* gA = A16 + (size_t)(rowBase + srow) * DD + scol;
  const u16* gB = B16 + (size_t)(colBase + srow) * DD + scol;
  const int ldsseg = wid * 512;                    // u16; +lane*16B by HW

  // stage round r (0/1) of half H (0/1), K-tile ktn, matrix M, buffer b
#define STG(M, b, ktn, H, r) \
  __builtin_amdgcn_global_load_lds( \
      (const AS1 void*)(g##M + (size_t)((H) * 128 + (r) * 64) * DD + (ktn) * 64), \
      (AS3 void*)((u16*)&s##M[b][0][0] + (H) * 8192 + (r) * 4096 + ldsseg), 16, 0, 0)
#define STGH(M, b, ktn, H) do { STG(M, b, ktn, H, 0); STG(M, b, ktn, H, 1); } while (0)

  // swizzled fragment read from buffer b, row, k-slice ks
#define LDF(M, b, row, ks) \
  (*(const f16x8*)((const u16*)&s##M[b][0][0] + (size_t)(row) * 64 + \
      (((ks) * 32 + quad * 8) ^ (((row) & 7) * 8))))

#define RDA(b, m0) { _Pragma("unroll") \
  for (int m = (m0); m < (m0) + 4; ++m) { _Pragma("unroll") \
    for (int ks = 0; ks < 2; ++ks) fa[m][ks] = LDF(A, b, wrow * 128 + m * 16 + lo, ks); } }
#define RDB(b, n0) { _Pragma("unroll") \
  for (int n = (n0); n < (n0) + 2; ++n) { _Pragma("unroll") \
    for (int ks = 0; ks < 2; ++ks) fb[n][ks] = LDF(B, b, wcol * 64 + n * 16 + lo, ks); } }
#define MM(m0, n0) { _Pragma("unroll") \
  for (int ks = 0; ks < 2; ++ks) { _Pragma("unroll") \
    for (int n = (n0); n < (n0) + 2; ++n) { _Pragma("unroll") \
      for (int m = (m0); m < (m0) + 4; ++m) \
        acc[m][n] = __builtin_amdgcn_mfma_f32_16x16x32_f16(fa[m][ks], fb[n][ks], acc[m][n], 0, 0, 0); } } }

#define SBAR  __builtin_amdgcn_s_barrier()
#define SCHB  __builtin_amdgcn_sched_barrier(0)
#define LGKM0 asm volatile("s_waitcnt lgkmcnt(0)" ::: "memory")
#define VMC(n) asm volatile("s_waitcnt vmcnt(" #n ")" ::: "memory")
#define PRIO1 __builtin_amdgcn_s_setprio(1)
#define PRIO0 __builtin_amdgcn_s_setprio(0)

  f32x4 acc[8][4];
#pragma unroll
  for (int i = 0; i < 8; ++i)
#pragma unroll
    for (int j = 0; j < 4; ++j) acc[i][j] = (f32x4){0.f, 0.f, 0.f, 0.f};
  f16x8 fa[8][2], fb[4][2];

  // prologue: stage T0 -> buf0, T1 -> buf1; wait only T0 (T1 in flight)
  STGH(A, 0, 0, 0); STGH(A, 0, 0, 1); STGH(B, 0, 0, 0); STGH(B, 0, 0, 1);
  STGH(A, 1, 1, 0); STGH(A, 1, 1, 1); STGH(B, 1, 1, 0); STGH(B, 1, 1, 1);
  VMC(8);
  SBAR;

#pragma unroll
  for (int it = 0; it < 2; ++it) {
    const int k0 = 2 * it;          // buf0 holds T(k0), buf1 holds T(k0+1)
    const bool more = (it < 1);

    // phase 1: Q0 of buf0; stage T(k0+1).B0 (iter>0; iter0: prologue did it)
    SCHB;
    RDA(0, 0); RDB(0, 0);
    if (it > 0) STGH(B, 1, k0 + 1, 0);
    SBAR; LGKM0;
    PRIO1; MM(0, 0); PRIO0;
    SBAR;
    // phase 2: Q1; stage T(k0+1).B1
    SCHB;
    RDA(0, 4);
    if (it > 0) STGH(B, 1, k0 + 1, 1);
    SBAR; LGKM0;
    PRIO1; MM(4, 0); PRIO0;
    SBAR;
    // phase 3: Q2; stage T(k0+2).A0 (buf0.A fully read after phase 2)
    SCHB;
    RDB(0, 2);
    if (more) STGH(A, 0, k0 + 2, 0);
    SBAR; LGKM0;
    PRIO1; MM(0, 2); PRIO0;
    SBAR;
    // phase 4: Q3; stage T(k0+2).A1; counted wait for buf1's pending B
    SCHB;
    if (more) STGH(A, 0, k0 + 2, 1);
    SBAR;
    PRIO1; MM(4, 2); PRIO0;
    if (more) { VMC(4); } else { VMC(0); }
    SBAR;
    // phase 5: Q0 of buf1; stage T(k0+2).B0 (buf0.B fully read after ph 3)
    SCHB;
    RDA(1, 0); RDB(1, 0);
    if (more) STGH(B, 0, k0 + 2, 0);
    SBAR; LGKM0;
    PRIO1; MM(0, 0); PRIO0;
    SBAR;
    // phase 6: Q1; stage T(k0+2).B1
    SCHB;
    RDA(1, 4);
    if (more) STGH(B, 0, k0 + 2, 1);
    SBAR; LGKM0;
    PRIO1; MM(4, 0); PRIO0;
    SBAR;
    // phase 7: Q2; stage T(k0+3).A0 (buf1.A fully read after phase 6)
    SCHB;
    RDB(1, 2);
    if (more) STGH(A, 1, k0 + 3, 0);
    SBAR; LGKM0;
    PRIO1; MM(0, 2); PRIO0;
    SBAR;
    // phase 8: Q3; stage T(k0+3).A1; counted wait -> T(k0+2) fully landed
    SCHB;
    if (more) STGH(A, 1, k0 + 3, 1);
    SBAR;
    PRIO1; MM(4, 2); PRIO0;
    if (more) VMC(4);
    SBAR;
  }
#undef STG
#undef STGH
#undef LDF
#undef RDA
#undef RDB
#undef MM

  // epilogue: e = exp(2c-2); row partials fp32, col partials fp64; candidates.
  // C/D layout: col = lo, row = quad*4 + reg  (m89/m91)
  float rowp[8][4];
  double colp[4];
#pragma unroll
  for (int i = 0; i < 8; ++i)
#pragma unroll
    for (int r = 0; r < 4; ++r) rowp[i][r] = 0.f;
#pragma unroll
  for (int j = 0; j < 4; ++j) colp[j] = 0.0;

#pragma unroll
  for (int i = 0; i < 8; ++i)
#pragma unroll
    for (int j = 0; j < 4; ++j)
#pragma unroll
      for (int r = 0; r < 4; ++r) {
        float c = acc[i][j][r];
        float e = __expf(2.f * c - 2.f);
        rowp[i][r] += e;
        colp[j] += (double)e;
        if (c >= CAND_T0) {
          int row = rowBase + wrow * 128 + i * 16 + quad * 4 + r;
          int col = colBase + wcol * 64 + j * 16 + lo;
          int idx = atomicAdd(cnt, 1);
          if (idx < ncap) cand[idx] = ((u32)row << 13) | (u32)col;
        }
      }

  // row sums: reduce over lo (16 lanes) -> this wave's 64 cols
#pragma unroll
  for (int i = 0; i < 8; ++i)
#pragma unroll
    for (int r = 0; r < 4; ++r) {
      float v = rowp[i][r];
#pragma unroll
      for (int off = 8; off; off >>= 1) v += __shfl_xor(v, off, 16);
      rowp[i][r] = v;
    }
  // col sums: reduce over quad -> this wave's 128 rows
#pragma unroll
  for (int j = 0; j < 4; ++j) {
    double v = colp[j];
    v += __shfl_xor(v, 16);
    v += __shfl_xor(v, 32);
    colp[j] = v;
  }

  // cross-wave combine: 4 wcol partials per row, 2 wrow partials per col
  if (wcol && lo == 0) {
#pragma unroll
    for (int i = 0; i < 8; ++i)
#pragma unroll
      for (int r = 0; r < 4; ++r)
        sRcomb[wcol][wrow][i * 16 + quad * 4 + r] = rowp[i][r];
  }
  if (wrow == 1 && quad == 0) {
#pragma unroll
    for (int j = 0; j < 4; ++j) sCcomb[wcol][j * 16 + lo] = colp[j];
  }
  __syncthreads();

  if (wcol == 0 && lo == 0) {
#pragma unroll
    for (int i = 0; i < 8; ++i)
#pragma unroll
      for (int r = 0; r < 4; ++r) {
        int idx = i * 16 + quad * 4 + r;
        float tot = rowp[i][r] + sRcomb[1][wrow][idx] + sRcomb[2][wrow][idx]
                  + sRcomb[3][wrow][idx];
        atomicAdd(&R[rowBase + wrow * 128 + idx], (double)tot);
      }
  }
  if (wrow == 0 && quad == 0) {
#pragma unroll
    for (int j = 0; j < 4; ++j) {
      int idx = j * 16 + lo;
      atomicAdd(&Cmy[colBase + wcol * 64 + idx], colp[j] + sCcomb[wcol][idx]);
    }
  }
}

// ---------------- fp32 fallback GEMM (used only if ws too small) ----------------
__global__ __launch_bounds__(256) void k_gemm_f32(
    const float* __restrict__ A, const float* __restrict__ B,
    double* __restrict__ R, double* __restrict__ CP,
    int* __restrict__ cnt, u32* __restrict__ cand, int ncap) {
  __shared__ float As[32][128];
  __shared__ float Bs[32][128];
  __shared__ double colLds[16][128];
  const int tid = threadIdx.x;
  const int tx = tid & 15, ty = tid >> 4;
  const int rowBase = blockIdx.y * 128;
  const int colBase = blockIdx.x * 128;
  float acc[8][8];
#pragma unroll
  for (int i = 0; i < 8; ++i)
#pragma unroll
    for (int j = 0; j < 8; ++j) acc[i][j] = 0.f;
  const int lr = tid >> 3;
  const int lc = (tid & 7) << 2;
  for (int kk = 0; kk < DD; kk += 32) {
#pragma unroll
    for (int r = 0; r < 4; ++r) {
      int row = lr + r * 32;
      float4 av = *(const float4*)(A + (size_t)(rowBase + row) * DD + kk + lc);
      float4 bv = *(const float4*)(B + (size_t)(colBase + row) * DD + kk + lc);
      As[lc + 0][row] = av.x; As[lc + 1][row] = av.y; As[lc + 2][row] = av.z; As[lc + 3][row] = av.w;
      Bs[lc + 0][row] = bv.x; Bs[lc + 1][row] = bv.y; Bs[lc + 2][row] = bv.z; Bs[lc + 3][row] = bv.w;
    }
    __syncthreads();
#pragma unroll 4
    for (int k = 0; k < 32; ++k) {
      float a[8], b[8];
      *(float4*)(a + 0) = *(const float4*)(&As[k][ty * 8 + 0]);
      *(float4*)(a + 4) = *(const float4*)(&As[k][ty * 8 + 4]);
      *(float4*)(b + 0) = *(const float4*)(&Bs[k][tx * 8 + 0]);
      *(float4*)(b + 4) = *(const float4*)(&Bs[k][tx * 8 + 4]);
#pragma unroll
      for (int i = 0; i < 8; ++i)
#pragma unroll
        for (int j = 0; j < 8; ++j)
          acc[i][j] = fmaf(a[i], b[j], acc[i][j]);
    }
    __syncthreads();
  }
  double colpart[8];
#pragma unroll
  for (int j = 0; j < 8; ++j) colpart[j] = 0.0;
#pragma unroll
  for (int i = 0; i < 8; ++i) {
    double rp = 0.0;
#pragma unroll
    for (int j = 0; j < 8; ++j) {
      float e = __expf(2.f * acc[i][j] - 2.f);
      rp += (double)e;
      colpart[j] += (double)e;
    }
#pragma unroll
    for (int off = 8; off; off >>= 1) rp += __shfl_down(rp, off, 16);
    if (tx == 0) atomicAdd(&R[rowBase + ty * 8 + i], rp);
  }
#pragma unroll
  for (int j = 0; j < 8; ++j) colLds[ty][tx * 8 + j] = colpart[j];
  __syncthreads();
  if (tid < 128) {
    double s = 0.0;
#pragma unroll
    for (int t = 0; t < 16; ++t) s += colLds[t][tid];
    atomicAdd(&CP[colBase + tid], s);   // partition 0 only
  }
#pragma unroll
  for (int i = 0; i < 8; ++i)
#pragma unroll
    for (int j = 0; j < 8; ++j) {
      if (acc[i][j] >= CAND_T0) {
        int idx = atomicAdd(cnt, 1);
        if (idx < ncap)
          cand[idx] = ((u32)(rowBase + ty * 8 + i) << 13) | (u32)(colBase + tx * 8 + j);
      }
    }
}

// One wave per candidate: exact fp64 dot, fp64 score, orderable u64 key.
__global__ __launch_bounds__(256) void k_score(
    const float* __restrict__ A, const float* __restrict__ B,
    const double* __restrict__ R, const double* __restrict__ CP,
    const int* __restrict__ cnt, const u32* __restrict__ cand,
    u64* __restrict__ keys, int ncap) {
  int w = (int)((blockIdx.x * 256 + threadIdx.x) >> 6);
  int lane = threadIdx.x & 63;
  int n = *cnt; if (n > ncap) n = ncap;
  if (w >= n) return;
  u32 mn = cand[w];
  int m = (int)(mn >> 13), nn = (int)(mn & 8191u);
  const float* ar = A + (size_t)m * DD;
  const float* br = B + (size_t)nn * DD;
  double s = 0.0;
#pragma unroll
  for (int d = 0; d < DD; d += 64)
    s = fma((double)ar[d + lane], (double)br[d + lane], s);
#pragma unroll
  for (int off = 32; off; off >>= 1) s += __shfl_down(s, off);
  if (lane == 0) {
    double Cn = 0.0;
#pragma unroll
    for (int x = 0; x < 8; ++x) Cn += CP[(size_t)x * ND + nn];
    double sc = exp(4.0 * s - 4.0) / (R[m] * Cn);
    keys[w] = (u64)__double_as_longlong(sc);
  }
}

// (key desc, flat-idx asc) strict order; idx unique so no true ties.
__device__ __forceinline__ bool is_worse(u64 ka, u32 ma, u64 kb, u32 mb) {
  return (ka < kb) || (ka == kb && ma > mb);
}

// Single-block top-256: register/shuffle bitonic. Fast path n<=2048, with
// dynamic merge depth (np=1024 when n<=1024 -> skip one bitonic level).
// Legacy 4096 LDS bitonic fallback.
__global__ __launch_bounds__(1024) void k_sort(
    const int* __restrict__ cnt, const u32* __restrict__ cand,
    const u64* __restrict__ keys, float* __restrict__ out, int ncap) {
  __shared__ u64 sk[NPAD];
  __shared__ u32 sm[NPAD];
  const int tid = threadIdx.x;
  const int lane = tid & 63;
  const int wid = tid >> 6;
  int m = *cnt; if (m > ncap) m = ncap;

  if (m <= 2048) {
    const int NP = (m <= 1024) ? 1024 : 2048;
    const int base = wid * 128;
    const int i0 = base + lane * 2;

    // wave-local sort of each 128-segment (reg/shuffle, zero barriers).
    // Padding segments (>= NP) sort trivially and are never merged/read.
    u64 k0 = (i0 < m) ? keys[i0] : 0;
    u64 k1 = (i0 + 1 < m) ? keys[i0 + 1] : 0;
    u32 m0 = (i0 < m) ? cand[i0] : 0xFFFFFFFFu;
    u32 m1 = (i0 + 1 < m) ? cand[i0 + 1] : 0xFFFFFFFFu;
#pragma unroll
    for (int k = 2; k <= 128; k <<= 1) {
#pragma unroll
      for (int j = k >> 1; j >= 1; j >>= 1) {
        const bool bf = ((i0 & k) == 0);
        if (j == 1) {
          bool sw = bf ? is_worse(k0, m0, k1, m1) : is_worse(k1, m1, k0, m0);
          if (sw) { u64 tk = k0; k0 = k1; k1 = tk; u32 tm = m0; m0 = m1; m1 = tm; }
        } else {
          const int j2 = j >> 1;
          const bool keepb = (bf == ((lane & j2) == 0));
          u64 pk0 = __shfl_xor(k0, j2); u32 pm0 = __shfl_xor(m0, j2);
          u64 pk1 = __shfl_xor(k1, j2); u32 pm1 = __shfl_xor(m1, j2);
          if (keepb == is_worse(k0, m0, pk0, pm0)) { k0 = pk0; m0 = pm0; }
          if (keepb == is_worse(k1, m1, pk1, pm1)) { k1 = pk1; m1 = pm1; }
        }
      }
    }
    sk[i0] = k0; sk[i0 + 1] = k1; sm[i0] = m0; sm[i0 + 1] = m1;
    __syncthreads();

    for (int k = 256; k <= NP; k <<= 1) {
      for (int j = k >> 1; j >= 128; j >>= 1) {
        for (int i = tid; i < NP; i += 1024) {
          int l = i ^ j;
          if (l > i) {
            u64 ki = sk[i], kl = sk[l];
            u32 mi = sm[i], ml = sm[l];
            bool bf = ((i & k) == 0);
            bool swp = bf ? is_worse(ki, mi, kl, ml) : is_worse(kl, ml, ki, mi);
            if (swp) { sk[i] = kl; sk[l] = ki; sm[i] = ml; sm[l] = mi; }
          }
        }
        __syncthreads();
      }
      if (i0 < NP) {
        k0 = sk[i0]; k1 = sk[i0 + 1]; m0 = sm[i0]; m1 = sm[i0 + 1];
        const bool bf = ((base & k) == 0);
#pragma unroll
        for (int j = 64; j >= 2; j >>= 1) {
          const int j2 = j >> 1;
          const bool keepb = (bf == ((lane & j2) == 0));
          u64 pk0 = __shfl_xor(k0, j2); u32 pm0 = __shfl_xor(m0, j2);
          u64 pk1 = __shfl_xor(k1, j2); u32 pm1 = __shfl_xor(m1, j2);
          if (keepb == is_worse(k0, m0, pk0, pm0)) { k0 = pk0; m0 = pm0; }
          if (keepb == is_worse(k1, m1, pk1, pm1)) { k1 = pk1; m1 = pm1; }
        }
        {
          bool sw = bf ? is_worse(k0, m0, k1, m1) : is_worse(k1, m1, k0, m0);
          if (sw) { u64 tk = k0; k0 = k1; k1 = tk; u32 tm = m0; m0 = m1; m1 = tm; }
        }
      }
      __syncthreads();
      if (i0 < NP) { sk[i0] = k0; sk[i0 + 1] = k1; sm[i0] = m0; sm[i0 + 1] = m1; }
      __syncthreads();
    }
  } else {
    for (int i = tid; i < NPAD; i += 1024) { sk[i] = 0; sm[i] = 0xFFFFFFFFu; }
    __syncthreads();
    for (int i = tid; i < m; i += 1024) { sk[i] = keys[i]; sm[i] = cand[i]; }
    __syncthreads();
    for (unsigned k = 2; k <= (unsigned)NPAD; k <<= 1) {
      for (unsigned j = k >> 1; j > 0; j >>= 1) {
        for (unsigned i = tid; i < (unsigned)NPAD; i += 1024) {
          unsigned l = i ^ j;
          if (l > i) {
            u64 ki = sk[i], kl = sk[l];
            u32 mi = sm[i], ml = sm[l];
            bool dir = ((i & k) == 0);
            bool swp = dir ? is_worse(ki, mi, kl, ml) : is_worse(kl, ml, ki, mi);
            if (swp) { sk[i] = kl; sk[l] = ki; sm[i] = ml; sm[l] = mi; }
          }
        }
        __syncthreads();
      }
    }
  }

  for (int r = tid; r < KTOP; r += 1024) {
    u32 mn = sm[r];
    u64 kk = sk[r];
    out[r] = (float)(mn >> 13);
    out[KTOP + r] = (float)(mn & 8191u);
    out[2 * KTOP + r] = (float)__longlong_as_double((long long)kk);
  }
}

extern "C" void kernel_launch(void* const* d_in, const int* in_sizes, int n_in,
                              void* d_out, int out_size, void* d_ws, size_t ws_size,
                              hipStream_t stream) {
  (void)in_sizes; (void)n_in; (void)out_size;
  const float* A = (const float*)d_in[0];  // ref_feats [8192,256]
  const float* B = (const float*)d_in[1];  // src_feats [8192,256]
  float* out = (float*)d_out;
  char* ws = (char*)d_ws;
  double* R = (double*)(ws + OFF_R);
  double* CP = (double*)(ws + OFF_CP);
  int* cnt = (int*)(ws + OFF_CNT);
  u32* cand = (u32*)(ws + OFF_CAND);
  u64* keys = (u64*)(ws + OFF_KEYS);

  if (ws_size >= (size_t)WS_REQ) {
    u16* A16p = (u16*)(ws + OFF_A16);
    u16* B16p = (u16*)(ws + OFF_B16);
    hipLaunchKernelGGL(k_prep2, dim3(2048), dim3(256), 0, stream,
                       A, B, A16p, B16p, R, CP, cnt);
    hipLaunchKernelGGL(k_gemm_mfma, dim3(1024), dim3(512), 0, stream,
                       A16p, B16p, R, CP, cnt, cand, NCAP);
  } else {
    hipLaunchKernelGGL(k_init, dim3(288), dim3(256), 0, stream, R, CP, cnt);
    hipLaunchKernelGGL(k_gemm_f32, dim3(ND / 128, MD / 128), dim3(256), 0, stream,
                       A, B, R, CP, cnt, cand, NCAP);
  }

  hipLaunchKernelGGL(k_score, dim3(NCAP / 4), dim3(256), 0, stream,
                     A, B, R, CP, cnt, cand, keys, NCAP);
  hipLaunchKernelGGL(k_sort, dim3(1), dim3(1024), 0, stream,
                     cnt, cand, keys, out, NCAP);
}

// Round 8
// 148.963 us; speedup vs baseline: 2.5931x; 1.0031x over previous
//
#include <hip/hip_runtime.h>

#define MD 8192
#define ND 8192
#define DD 256
#define KTOP 256
#define CAND_T0 0.26f
#define NCAP 4096
#define NPAD 4096

typedef unsigned int u32;
typedef unsigned short u16;
typedef unsigned long long u64;

// workspace layout (bytes)
#define OFF_R    0                  // double R[8192]          64 KB
#define OFF_CP   65536              // double CP[8][8192]     512 KB
#define OFF_CNT  589824             // int
#define OFF_CAND 589952             // u32 cand[4096]          16 KB
#define OFF_KEYS 606336             // u64 keys[4096]          32 KB
#define OFF_A16  655360             // u16 A16[8192*256]        4 MB
#define OFF_B16  (OFF_A16 + 4194304)
#define WS_REQ   (OFF_B16 + 4194304)

using f16x8 = __attribute__((ext_vector_type(8))) _Float16;
using f32x4  = __attribute__((ext_vector_type(4))) float;

#define AS1 __attribute__((address_space(1)))
#define AS3 __attribute__((address_space(3)))

__device__ __forceinline__ u16 f2h(float x) {
  union { _Float16 h; u16 u; } v;
  v.h = (_Float16)x;   // v_cvt_f16_f32, RNE
  return v.u;
}

// fallback-path init: zero R, CP, cnt (grid-stride)
__global__ void k_init(double* __restrict__ R, double* __restrict__ CP, int* __restrict__ cnt) {
  int stride = gridDim.x * blockDim.x;
  for (int i = blockIdx.x * blockDim.x + threadIdx.x; i < MD + 8 * ND; i += stride) {
    if (i < MD) R[i] = 0.0;
    else CP[i - MD] = 0.0;
  }
  if (blockIdx.x == 0 && threadIdx.x == 0) *cnt = 0;
}

// Fused: zero R/CP/cnt + convert BOTH matrices to single fp16 planes.
// R12: fp16 single-product (verified absmax 0). c only feeds the cand
// threshold (noise 1.2e-5 << 0.26 margin) and row/col sums; top-256
// numerators recomputed exactly in fp64 by k_score.
__global__ __launch_bounds__(256) void k_prep2(
    const float* __restrict__ A, const float* __restrict__ B,
    u16* __restrict__ A16p, u16* __restrict__ B16p,
    double* __restrict__ R, double* __restrict__ CP, int* __restrict__ cnt) {
  const int gid = blockIdx.x * 256 + threadIdx.x;
  if (gid < MD) R[gid] = 0.0;
  if (gid < 8 * ND) CP[gid] = 0.0;
  if (gid == 0) *cnt = 0;

  {
    float4 v = ((const float4*)A)[gid];
    ushort4 h;
    h.x = f2h(v.x); h.y = f2h(v.y); h.z = f2h(v.z); h.w = f2h(v.w);
    ((ushort4*)A16p)[gid] = h;
  }
  {
    float4 v = ((const float4*)B)[gid];
    ushort4 h;
    h.x = f2h(v.x); h.y = f2h(v.y); h.z = f2h(v.z); h.w = f2h(v.w);
    ((ushort4*)B16p)[gid] = h;
  }
}

// ---------------- MFMA fp16 GEMM (R19: R18 + parity fix) -------------------
// R18 post-mortem: absmax 8002 from ONE bug — buffer parity written as
// cur=(ps^kt)&1, but global step = ps*8+kt has parity kt&1 (8 is even), so
// odd passes read the opposite buffer from the one the cross-pass prefetch
// filled. R19: cur = kt&1. Parity flows across pass boundaries (pass ends
// cur=1, prefetch -> buf0, next pass starts cur=0). All else = R18:
//  - R13's K-loop/LDS/swizzle (0 bank conflicts), (256,4), ~14 waves/CU
//    cross-block overlap (the regime R15-R17 proved 256^2 1-block lacks);
//  - each block sweeps 4 adjacent 128-col tiles: prologue drain 1x not 4x
//    (kt=7 of pass p prefetches kt=0 of pass p+1, steady-state hazard
//    discipline), row-sum reduce + R atomics 1x (rowp over 512 cols).
__global__ __launch_bounds__(256, 4) void k_gemm_mfma(
    const u16* __restrict__ A16, const u16* __restrict__ B16,
    double* __restrict__ R, double* __restrict__ CP,
    int* __restrict__ cnt, u32* __restrict__ cand, int ncap) {
  __shared__ u16 sA[2][128][32];   // 16 KB
  __shared__ u16 sB[2][128][32];   // 16 KB
  __shared__ float sR[2][64];      // [wrow][i*16+quad*4+r]  from wcol==1
  __shared__ double sC[2][64];     // [wcol][j*16+lo]        from wrow==1

  const int tid = threadIdx.x;
  const int lane = tid & 63;
  const int wid = tid >> 6;           // 0..3
  const int wrow = wid >> 1, wcol = wid & 1;

  // XCD-aware block swizzle (1-D grid of 1024; 1024%8==0 -> bijective)
  const int g = blockIdx.x;
  const int xcd = g & 7;
  const int l = g >> 3;               // 0..127
  const int rowTile = xcd * 8 + (l & 7);   // 0..63
  const int colGroup = l >> 3;             // 0..15
  const int rowBase = rowTile * 128;
  const int colBase = colGroup * 512;      // 4 x 128-col passes
  double* Cmy = CP + (size_t)xcd * ND;

  const int quad = lane >> 4, lo = lane & 15;
  const int sw = (lo >> 1) & 3;
  const int cswz = (lane & 3) ^ ((lane >> 3) & 3);

  // staging: waves 0,1 -> sA halves; waves 2,3 -> sB halves (4 chunks each).
  // B waves advance 128 rows per pass (psstride); A waves reuse the panel.
  const int half = wid & 1;
  u16* lb0;
  const u16* gb;
  size_t psstride;
  if (wid < 2) {
    lb0 = &sA[0][half * 64][0];
    gb = A16 + (size_t)(rowBase + half * 64 + (lane >> 2)) * DD + cswz * 8;
    psstride = 0;
  } else {
    lb0 = &sB[0][half * 64][0];
    gb = B16 + (size_t)(colBase + half * 64 + (lane >> 2)) * DD + cswz * 8;
    psstride = (size_t)128 * DD;
  }

  // STAGE(buf, kt, ps): this wave's 4 chunks of K-step kt, pass ps.
  // Buffer stride: sA[1]-sA[0] = 128*32 = 4096 u16.
#define STAGE(b, kt, ps) \
  do { \
    _Pragma("unroll") \
    for (int ch = 0; ch < 4; ++ch) { \
      const u16* gp = gb + (size_t)(ps) * psstride + (size_t)(ch * 16) * DD + (kt) * 32; \
      __builtin_amdgcn_global_load_lds((const AS1 void*)gp, \
          (AS3 void*)(lb0 + (b) * 4096 + ch * 512), 16, 0, 0); \
    } \
  } while (0)

  const int cq = (quad ^ sw) * 8;

  float rowp[4][4];
#pragma unroll
  for (int i = 0; i < 4; ++i)
#pragma unroll
    for (int r = 0; r < 4; ++r) rowp[i][r] = 0.f;

  // prologue: stage pass0/kt0 into buf0, drain once for the whole block
  STAGE(0, 0, 0);
  __syncthreads();

  for (int ps = 0; ps < 4; ++ps) {
    f32x4 acc[4][4];
#pragma unroll
    for (int i = 0; i < 4; ++i)
#pragma unroll
      for (int j = 0; j < 4; ++j) acc[i][j] = (f32x4){0.f, 0.f, 0.f, 0.f};

#pragma unroll
    for (int kt = 0; kt < 8; ++kt) {
      const int cur = kt & 1;   // global step = ps*8+kt; 8 even -> parity kt&1
      if (kt < 7) STAGE(cur ^ 1, kt + 1, ps);
      else if (ps < 3) STAGE(cur ^ 1, 0, ps + 1);   // cross-pass prefetch

      f16x8 fa[4];
#pragma unroll
      for (int t = 0; t < 4; ++t)
        fa[t] = *(const f16x8*)&sA[cur][wrow * 64 + t * 16 + lo][cq];
#pragma unroll
      for (int j = 0; j < 4; ++j) {
        f16x8 fb = *(const f16x8*)&sB[cur][wcol * 64 + j * 16 + lo][cq];
#pragma unroll
        for (int i = 0; i < 4; ++i)
          acc[i][j] = __builtin_amdgcn_mfma_f32_16x16x32_f16(fa[i], fb, acc[i][j], 0, 0, 0);
      }
      // barrier: all waves done reading buf[cur] (lgkm) + staged loads for
      // buf[cur^1] landed (vmcnt) -> next step / next pass may proceed.
      __syncthreads();
    }

    // per-pass epilogue: e = exp(2c-2); rowp accumulates across passes,
    // colp + cand are per-pass. C/D layout: col=lo, row=quad*4+reg (m89/m91)
    const int pcol = colBase + ps * 128;
    double colp[4];
#pragma unroll
    for (int j = 0; j < 4; ++j) colp[j] = 0.0;

#pragma unroll
    for (int i = 0; i < 4; ++i)
#pragma unroll
      for (int j = 0; j < 4; ++j)
#pragma unroll
        for (int r = 0; r < 4; ++r) {
          float c = acc[i][j][r];
          float e = __expf(2.f * c - 2.f);
          rowp[i][r] += e;
          colp[j] += (double)e;
          if (c >= CAND_T0) {
            int row = rowBase + wrow * 64 + i * 16 + quad * 4 + r;
            int col = pcol + wcol * 64 + j * 16 + lo;
            int idx = atomicAdd(cnt, 1);
            if (idx < ncap) cand[idx] = ((u32)row << 13) | (u32)col;
          }
        }

    // col sums: reduce over quad -> this wave's 64 rows; combine 2 wrow
#pragma unroll
    for (int j = 0; j < 4; ++j) {
      double v = colp[j];
      v += __shfl_xor(v, 16);
      v += __shfl_xor(v, 32);
      colp[j] = v;
    }
    if (wrow == 1 && quad == 0) {
#pragma unroll
      for (int j = 0; j < 4; ++j) sC[wcol][j * 16 + lo] = colp[j];
    }
    __syncthreads();
    if (wrow == 0 && quad == 0) {
#pragma unroll
      for (int j = 0; j < 4; ++j) {
        int idx = j * 16 + lo;
        atomicAdd(&Cmy[pcol + wcol * 64 + idx], colp[j] + sC[wcol][idx]);
      }
    }
    // sC reuse in next pass is ordered by the next K-loop's barriers.
  }

  // final: row sums over all 512 cols (reduce over lo; combine 2 wcol)
#pragma unroll
  for (int i = 0; i < 4; ++i)
#pragma unroll
    for (int r = 0; r < 4; ++r) {
      float v = rowp[i][r];
#pragma unroll
      for (int off = 8; off; off >>= 1) v += __shfl_xor(v, off, 16);
      rowp[i][r] = v;
    }
  if (wcol == 1 && lo == 0) {
#pragma unroll
    for (int i = 0; i < 4; ++i)
#pragma unroll
      for (int r = 0; r < 4; ++r) sR[wrow][i * 16 + quad * 4 + r] = rowp[i][r];
  }
  __syncthreads();
  if (wcol == 0 && lo == 0) {
#pragma unroll
    for (int i = 0; i < 4; ++i)
#pragma unroll
      for (int r = 0; r < 4; ++r) {
        int idx = i * 16 + quad * 4 + r;
        atomicAdd(&R[rowBase + wrow * 64 + idx], (double)(rowp[i][r] + sR[wrow][idx]));
      }
  }
#undef STAGE
}

// ---------------- fp32 fallback GEMM (used only if ws too small) ----------------
__global__ __launch_bounds__(256) void k_gemm_f32(
    const float* __restrict__ A, const float* __restrict__ B,
    double* __restrict__ R, double* __restrict__ CP,
    int* __restrict__ cnt, u32* __restrict__ cand, int ncap) {
  __shared__ float As[32][128];
  __shared__ float Bs[32][128];
  __shared__ double colLds[16][128];
  const int tid = threadIdx.x;
  const int tx = tid & 15, ty = tid >> 4;
  const int rowBase = blockIdx.y * 128;
  const int colBase = blockIdx.x * 128;
  float acc[8][8];
#pragma unroll
  for (int i = 0; i < 8; ++i)
#pragma unroll
    for (int j = 0; j < 8; ++j) acc[i][j] = 0.f;
  const int lr = tid >> 3;
  const int lc = (tid & 7) << 2;
  for (int kk = 0; kk < DD; kk += 32) {
#pragma unroll
    for (int r = 0; r < 4; ++r) {
      int row = lr + r * 32;
      float4 av = *(const float4*)(A + (size_t)(rowBase + row) * DD + kk + lc);
      float4 bv = *(const float4*)(B + (size_t)(colBase + row) * DD + kk + lc);
      As[lc + 0][row] = av.x; As[lc + 1][row] = av.y; As[lc + 2][row] = av.z; As[lc + 3][row] = av.w;
      Bs[lc + 0][row] = bv.x; Bs[lc + 1][row] = bv.y; Bs[lc + 2][row] = bv.z; Bs[lc + 3][row] = bv.w;
    }
    __syncthreads();
#pragma unroll 4
    for (int k = 0; k < 32; ++k) {
      float a[8], b[8];
      *(float4*)(a + 0) = *(const float4*)(&As[k][ty * 8 + 0]);
      *(float4*)(a + 4) = *(const float4*)(&As[k][ty * 8 + 4]);
      *(float4*)(b + 0) = *(const float4*)(&Bs[k][tx * 8 + 0]);
      *(float4*)(b + 4) = *(const float4*)(&Bs[k][tx * 8 + 4]);
#pragma unroll
      for (int i = 0; i < 8; ++i)
#pragma unroll
        for (int j = 0; j < 8; ++j)
          acc[i][j] = fmaf(a[i], b[j], acc[i][j]);
    }
    __syncthreads();
  }
  double colpart[8];
#pragma unroll
  for (int j = 0; j < 8; ++j) colpart[j] = 0.0;
#pragma unroll
  for (int i = 0; i < 8; ++i) {
    double rp = 0.0;
#pragma unroll
    for (int j = 0; j < 8; ++j) {
      float e = __expf(2.f * acc[i][j] - 2.f);
      rp += (double)e;
      colpart[j] += (double)e;
    }
#pragma unroll
    for (int off = 8; off; off >>= 1) rp += __shfl_down(rp, off, 16);
    if (tx == 0) atomicAdd(&R[rowBase + ty * 8 + i], rp);
  }
#pragma unroll
  for (int j = 0; j < 8; ++j) colLds[ty][tx * 8 + j] = colpart[j];
  __syncthreads();
  if (tid < 128) {
    double s = 0.0;
#pragma unroll
    for (int t = 0; t < 16; ++t) s += colLds[t][tid];
    atomicAdd(&CP[colBase + tid], s);   // partition 0 only
  }
#pragma unroll
  for (int i = 0; i < 8; ++i)
#pragma unroll
    for (int j = 0; j < 8; ++j) {
      if (acc[i][j] >= CAND_T0) {
        int idx = atomicAdd(cnt, 1);
        if (idx < ncap)
          cand[idx] = ((u32)(rowBase + ty * 8 + i) << 13) | (u32)(colBase + tx * 8 + j);
      }
    }
}

// One wave per candidate: exact fp64 dot, fp64 score, orderable u64 key.
__global__ __launch_bounds__(256) void k_score(
    const float* __restrict__ A, const float* __restrict__ B,
    const double* __restrict__ R, const double* __restrict__ CP,
    const int* __restrict__ cnt, const u32* __restrict__ cand,
    u64* __restrict__ keys, int ncap) {
  int w = (int)((blockIdx.x * 256 + threadIdx.x) >> 6);
  int lane = threadIdx.x & 63;
  int n = *cnt; if (n > ncap) n = ncap;
  if (w >= n) return;
  u32 mn = cand[w];
  int m = (int)(mn >> 13), nn = (int)(mn & 8191u);
  const float* ar = A + (size_t)m * DD;
  const float* br = B + (size_t)nn * DD;
  double s = 0.0;
#pragma unroll
  for (int d = 0; d < DD; d += 64)
    s = fma((double)ar[d + lane], (double)br[d + lane], s);
#pragma unroll
  for (int off = 32; off; off >>= 1) s += __shfl_down(s, off);
  if (lane == 0) {
    double Cn = 0.0;
#pragma unroll
    for (int x = 0; x < 8; ++x) Cn += CP[(size_t)x * ND + nn];
    double sc = exp(4.0 * s - 4.0) / (R[m] * Cn);
    keys[w] = (u64)__double_as_longlong(sc);
  }
}

// (key desc, flat-idx asc) strict order; idx unique so no true ties.
__device__ __forceinline__ bool is_worse(u64 ka, u32 ma, u64 kb, u32 mb) {
  return (ka < kb) || (ka == kb && ma > mb);
}

// Single-block top-256: register/shuffle bitonic. Fast path n<=2048, with
// dynamic merge depth (np=1024 when n<=1024 -> skip one bitonic level).
// Legacy 4096 LDS bitonic fallback.
__global__ __launch_bounds__(1024) void k_sort(
    const int* __restrict__ cnt, const u32* __restrict__ cand,
    const u64* __restrict__ keys, float* __restrict__ out, int ncap) {
  __shared__ u64 sk[NPAD];
  __shared__ u32 sm[NPAD];
  const int tid = threadIdx.x;
  const int lane = tid & 63;
  const int wid = tid >> 6;
  int m = *cnt; if (m > ncap) m = ncap;

  if (m <= 2048) {
    const int NP = (m <= 1024) ? 1024 : 2048;
    const int base = wid * 128;
    const int i0 = base + lane * 2;

    // wave-local sort of each 128-segment (reg/shuffle, zero barriers).
    // Padding segments (>= NP) sort trivially and are never merged/read.
    u64 k0 = (i0 < m) ? keys[i0] : 0;
    u64 k1 = (i0 + 1 < m) ? keys[i0 + 1] : 0;
    u32 m0 = (i0 < m) ? cand[i0] : 0xFFFFFFFFu;
    u32 m1 = (i0 + 1 < m) ? cand[i0 + 1] : 0xFFFFFFFFu;
#pragma unroll
    for (int k = 2; k <= 128; k <<= 1) {
#pragma unroll
      for (int j = k >> 1; j >= 1; j >>= 1) {
        const bool bf = ((i0 & k) == 0);
        if (j == 1) {
          bool sw = bf ? is_worse(k0, m0, k1, m1) : is_worse(k1, m1, k0, m0);
          if (sw) { u64 tk = k0; k0 = k1; k1 = tk; u32 tm = m0; m0 = m1; m1 = tm; }
        } else {
          const int j2 = j >> 1;
          const bool keepb = (bf == ((lane & j2) == 0));
          u64 pk0 = __shfl_xor(k0, j2); u32 pm0 = __shfl_xor(m0, j2);
          u64 pk1 = __shfl_xor(k1, j2); u32 pm1 = __shfl_xor(m1, j2);
          if (keepb == is_worse(k0, m0, pk0, pm0)) { k0 = pk0; m0 = pm0; }
          if (keepb == is_worse(k1, m1, pk1, pm1)) { k1 = pk1; m1 = pm1; }
        }
      }
    }
    sk[i0] = k0; sk[i0 + 1] = k1; sm[i0] = m0; sm[i0 + 1] = m1;
    __syncthreads();

    for (int k = 256; k <= NP; k <<= 1) {
      for (int j = k >> 1; j >= 128; j >>= 1) {
        for (int i = tid; i < NP; i += 1024) {
          int l = i ^ j;
          if (l > i) {
            u64 ki = sk[i], kl = sk[l];
            u32 mi = sm[i], ml = sm[l];
            bool bf = ((i & k) == 0);
            bool swp = bf ? is_worse(ki, mi, kl, ml) : is_worse(kl, ml, ki, mi);
            if (swp) { sk[i] = kl; sk[l] = ki; sm[i] = ml; sm[l] = mi; }
          }
        }
        __syncthreads();
      }
      if (i0 < NP) {
        k0 = sk[i0]; k1 = sk[i0 + 1]; m0 = sm[i0]; m1 = sm[i0 + 1];
        const bool bf = ((base & k) == 0);
#pragma unroll
        for (int j = 64; j >= 2; j >>= 1) {
          const int j2 = j >> 1;
          const bool keepb = (bf == ((lane & j2) == 0));
          u64 pk0 = __shfl_xor(k0, j2); u32 pm0 = __shfl_xor(m0, j2);
          u64 pk1 = __shfl_xor(k1, j2); u32 pm1 = __shfl_xor(m1, j2);
          if (keepb == is_worse(k0, m0, pk0, pm0)) { k0 = pk0; m0 = pm0; }
          if (keepb == is_worse(k1, m1, pk1, pm1)) { k1 = pk1; m1 = pm1; }
        }
        {
          bool sw = bf ? is_worse(k0, m0, k1, m1) : is_worse(k1, m1, k0, m0);
          if (sw) { u64 tk = k0; k0 = k1; k1 = tk; u32 tm = m0; m0 = m1; m1 = tm; }
        }
      }
      __syncthreads();
      if (i0 < NP) { sk[i0] = k0; sk[i0 + 1] = k1; sm[i0] = m0; sm[i0 + 1] = m1; }
      __syncthreads();
    }
  } else {
    for (int i = tid; i < NPAD; i += 1024) { sk[i] = 0; sm[i] = 0xFFFFFFFFu; }
    __syncthreads();
    for (int i = tid; i < m; i += 1024) { sk[i] = keys[i]; sm[i] = cand[i]; }
    __syncthreads();
    for (unsigned k = 2; k <= (unsigned)NPAD; k <<= 1) {
      for (unsigned j = k >> 1; j > 0; j >>= 1) {
        for (unsigned i = tid; i < (unsigned)NPAD; i += 1024) {
          unsigned l = i ^ j;
          if (l > i) {
            u64 ki = sk[i], kl = sk[l];
            u32 mi = sm[i], ml = sm[l];
            bool dir = ((i & k) == 0);
            bool swp = dir ? is_worse(ki, mi, kl, ml) : is_worse(kl, ml, ki, mi);
            if (swp) { sk[i] = kl; sk[l] = ki; sm[i] = ml; sm[l] = mi; }
          }
        }
        __syncthreads();
      }
    }
  }

  for (int r = tid; r < KTOP; r += 1024) {
    u32 mn = sm[r];
    u64 kk = sk[r];
    out[r] = (float)(mn >> 13);
    out[KTOP + r] = (float)(mn & 8191u);
    out[2 * KTOP + r] = (float)__longlong_as_double((long long)kk);
  }
}

extern "C" void kernel_launch(void* const* d_in, const int* in_sizes, int n_in,
                              void* d_out, int out_size, void* d_ws, size_t ws_size,
                              hipStream_t stream) {
  (void)in_sizes; (void)n_in; (void)out_size;
  const float* A = (const float*)d_in[0];  // ref_feats [8192,256]
  const float* B = (const float*)d_in[1];  // src_feats [8192,256]
  float* out = (float*)d_out;
  char* ws = (char*)d_ws;
  double* R = (double*)(ws + OFF_R);
  double* CP = (double*)(ws + OFF_CP);
  int* cnt = (int*)(ws + OFF_CNT);
  u32* cand = (u32*)(ws + OFF_CAND);
  u64* keys = (u64*)(ws + OFF_KEYS);

  if (ws_size >= (size_t)WS_REQ) {
    u16* A16p = (u16*)(ws + OFF_A16);
    u16* B16p = (u16*)(ws + OFF_B16);
    hipLaunchKernelGGL(k_prep2, dim3(2048), dim3(256), 0, stream,
                       A, B, A16p, B16p, R, CP, cnt);
    hipLaunchKernelGGL(k_gemm_mfma, dim3(1024), dim3(256), 0, stream,
                       A16p, B16p, R, CP, cnt, cand, NCAP);
  } else {
    hipLaunchKernelGGL(k_init, dim3(288), dim3(256), 0, stream, R, CP, cnt);
    hipLaunchKernelGGL(k_gemm_f32, dim3(ND / 128, MD / 128), dim3(256), 0, stream,
                       A, B, R, CP, cnt, cand, NCAP);
  }

  hipLaunchKernelGGL(k_score, dim3(NCAP / 4), dim3(256), 0, stream,
                     A, B, R, CP, cnt, cand, keys, NCAP);
  hipLaunchKernelGGL(k_sort, dim3(1), dim3(1024), 0, stream,
                     cnt, cand, keys, out, NCAP);
}

// Round 9
// 139.889 us; speedup vs baseline: 2.7613x; 1.0649x over previous
//
#include <hip/hip_runtime.h>

#define MD 8192
#define ND 8192
#define DD 256
#define KTOP 256
#define CAND_T0 0.26f
#define NCAP 4096
#define NPAD 4096

typedef unsigned int u32;
typedef unsigned short u16;
typedef unsigned long long u64;

// workspace layout (bytes)
#define OFF_R    0                  // double R[8192]          64 KB
#define OFF_CP   65536              // double CP[8][8192]     512 KB
#define OFF_CNT  589824             // int
#define OFF_CAND 589952             // u32 cand[4096]          16 KB
#define OFF_KEYS 606336             // u64 keys[4096]          32 KB
#define OFF_A16  655360             // u16 A16[8192*256]        4 MB
#define OFF_B16  (OFF_A16 + 4194304)
#define WS_REQ   (OFF_B16 + 4194304)

using f16x8 = __attribute__((ext_vector_type(8))) _Float16;
using f32x4  = __attribute__((ext_vector_type(4))) float;

#define AS1 __attribute__((address_space(1)))
#define AS3 __attribute__((address_space(3)))

__device__ __forceinline__ u16 f2h(float x) {
  union { _Float16 h; u16 u; } v;
  v.h = (_Float16)x;   // v_cvt_f16_f32, RNE
  return v.u;
}

// fallback-path init: zero R, CP, cnt (grid-stride)
__global__ void k_init(double* __restrict__ R, double* __restrict__ CP, int* __restrict__ cnt) {
  int stride = gridDim.x * blockDim.x;
  for (int i = blockIdx.x * blockDim.x + threadIdx.x; i < MD + 8 * ND; i += stride) {
    if (i < MD) R[i] = 0.0;
    else CP[i - MD] = 0.0;
  }
  if (blockIdx.x == 0 && threadIdx.x == 0) *cnt = 0;
}

// Fused: zero R/CP/cnt + convert BOTH matrices to single fp16 planes.
// R12: fp16 single-product (verified absmax 0). c only feeds the cand
// threshold (noise 1.2e-5 << 0.26 margin) and row/col sums; top-256
// numerators recomputed exactly in fp64 by k_score.
__global__ __launch_bounds__(256) void k_prep2(
    const float* __restrict__ A, const float* __restrict__ B,
    u16* __restrict__ A16p, u16* __restrict__ B16p,
    double* __restrict__ R, double* __restrict__ CP, int* __restrict__ cnt) {
  const int gid = blockIdx.x * 256 + threadIdx.x;
  if (gid < MD) R[gid] = 0.0;
  if (gid < 8 * ND) CP[gid] = 0.0;
  if (gid == 0) *cnt = 0;

  {
    float4 v = ((const float4*)A)[gid];
    ushort4 h;
    h.x = f2h(v.x); h.y = f2h(v.y); h.z = f2h(v.z); h.w = f2h(v.w);
    ((ushort4*)A16p)[gid] = h;
  }
  {
    float4 v = ((const float4*)B)[gid];
    ushort4 h;
    h.x = f2h(v.x); h.y = f2h(v.y); h.z = f2h(v.z); h.w = f2h(v.w);
    ((ushort4*)B16p)[gid] = h;
  }
}

// ---------------- MFMA fp16 GEMM (R20: R13 base + distance-2 prefetch) -----
// R18/R19 post-mortem: multi-col-tile passes regressed (68.5 us, WRITE 84MB
// from held-live state); REVERTED to R13's exact shape (4096 blocks, one
// 128x128 tile, rowp after loop — verified 63 us).
// R20's single change: 3 LDS buffers + prefetch distance 2 + COUNTED vmcnt.
// R13 issued kt+1's staging at step kt and drained vmcnt(0) at the step-end
// __syncthreads: cover = 1 compute phase (~450 cy) < load latency (~600-900)
// -> ~200-400 cy stall/step (MfmaUtil 21%). Now step kt stages buf[(kt+2)%3]
// and step-end is sched_barrier(0); vmcnt(4); s_barrier — kt+1's 4 loads
// retired, kt+2's stay in flight; cover = 2 phases >= latency.
// Hazards: write target (kt+2)%3 last read at kt-1 (barrier between);
// buf[kt%3] reads are pinned above the barrier by sched_barrier(0) (rule
// #18), overwrite happens at kt+1 after it. Per-wave 4 loads/step, in-order
// vmcnt (m135). LDS 48KB -> 3 blocks/CU (~12 waves, = R13's measured occ).
__global__ __launch_bounds__(256, 3) void k_gemm_mfma(
    const u16* __restrict__ A16, const u16* __restrict__ B16,
    double* __restrict__ R, double* __restrict__ CP,
    int* __restrict__ cnt, u32* __restrict__ cand, int ncap) {
  __shared__ u16 sA[3][128][32];   // 24 KB
  __shared__ u16 sB[3][128][32];   // 24 KB
  __shared__ float sR[2][64];      // [wrow][i*16+quad*4+r]  from wcol==1
  __shared__ double sC[2][64];     // [wcol][j*16+lo]        from wrow==1

  const int tid = threadIdx.x;
  const int lane = tid & 63;
  const int wid = tid >> 6;           // 0..3
  const int wrow = wid >> 1, wcol = wid & 1;

  // XCD-aware block swizzle (1-D grid of 4096)
  const int g = blockIdx.x;
  const int xcd = g & 7;
  const int l = g >> 3;               // 0..511
  const int rowTile = xcd * 8 + (l & 7);
  const int colTile = l >> 3;
  const int rowBase = rowTile * 128;
  const int colBase = colTile * 128;
  double* Cmy = CP + (size_t)xcd * ND;

  const int quad = lane >> 4, lo = lane & 15;
  const int sw = (lo >> 1) & 3;
  const int cswz = (lane & 3) ^ ((lane >> 3) & 3);

  // staging: waves 0,1 -> sA halves; waves 2,3 -> sB halves (4 chunks each)
  const int half = wid & 1;
  u16* lb0;
  const u16* gbl;
  if (wid < 2) {
    lb0 = &sA[0][half * 64][0];
    gbl = A16 + (size_t)(rowBase + half * 64 + (lane >> 2)) * DD + cswz * 8;
  } else {
    lb0 = &sB[0][half * 64][0];
    gbl = B16 + (size_t)(colBase + half * 64 + (lane >> 2)) * DD + cswz * 8;
  }

  // STAGE(b, kt): this wave's 4 chunks for K-step kt into buffer b (0..2).
  // Buffer stride: sA[1]-sA[0] = 128*32 = 4096 u16 (same for sB).
#define STAGE(b, kt) \
  do { \
    _Pragma("unroll") \
    for (int ch = 0; ch < 4; ++ch) { \
      const u16* gp = gbl + (size_t)(ch * 16) * DD + (kt) * 32; \
      __builtin_amdgcn_global_load_lds((const AS1 void*)gp, \
          (AS3 void*)(lb0 + (b) * 4096 + ch * 512), 16, 0, 0); \
    } \
  } while (0)

  f32x4 acc[4][4];
#pragma unroll
  for (int i = 0; i < 4; ++i)
#pragma unroll
    for (int j = 0; j < 4; ++j) acc[i][j] = (f32x4){0.f, 0.f, 0.f, 0.f};

  const int cq = (quad ^ sw) * 8;

  // prologue: stage kt=0 -> buf0, kt=1 -> buf1; wait only kt=0 (4 of 8)
  STAGE(0, 0);
  STAGE(1, 1);
  asm volatile("s_waitcnt vmcnt(4)" ::: "memory");
  __builtin_amdgcn_s_barrier();

#pragma unroll
  for (int kt = 0; kt < 8; ++kt) {
    const int cur = kt % 3;             // compile-time after full unroll
    if (kt < 6) STAGE((kt + 2) % 3, kt + 2);   // distance-2 prefetch

    f16x8 fa[4];
#pragma unroll
    for (int t = 0; t < 4; ++t)
      fa[t] = *(const f16x8*)&sA[cur][wrow * 64 + t * 16 + lo][cq];
#pragma unroll
    for (int j = 0; j < 4; ++j) {
      f16x8 fb = *(const f16x8*)&sB[cur][wcol * 64 + j * 16 + lo][cq];
#pragma unroll
      for (int i = 0; i < 4; ++i)
        acc[i][j] = __builtin_amdgcn_mfma_f32_16x16x32_f16(fa[i], fb, acc[i][j], 0, 0, 0);
    }
    // step end: pin reads+MFMA above; counted wait (kt+1 landed, kt+2 in
    // flight); raw barrier (NOT __syncthreads — that would drain vmcnt(0)).
    __builtin_amdgcn_sched_barrier(0);
    if (kt < 6)      asm volatile("s_waitcnt vmcnt(4)" ::: "memory");
    else if (kt == 6) asm volatile("s_waitcnt vmcnt(0)" ::: "memory");
    __builtin_amdgcn_s_barrier();
  }
#undef STAGE

  // epilogue: e = exp(2c-2); row partials fp32, col partials fp64; candidates.
  // C/D layout: col = lo, row = quad*4 + reg  (m89/m91)
  float rowp[4][4];
  double colp[4];
#pragma unroll
  for (int i = 0; i < 4; ++i)
#pragma unroll
    for (int r = 0; r < 4; ++r) rowp[i][r] = 0.f;
#pragma unroll
  for (int j = 0; j < 4; ++j) colp[j] = 0.0;

#pragma unroll
  for (int i = 0; i < 4; ++i)
#pragma unroll
    for (int j = 0; j < 4; ++j)
#pragma unroll
      for (int r = 0; r < 4; ++r) {
        float c = acc[i][j][r];
        float e = __expf(2.f * c - 2.f);
        rowp[i][r] += e;
        colp[j] += (double)e;
        if (c >= CAND_T0) {
          int row = rowBase + wrow * 64 + i * 16 + quad * 4 + r;
          int col = colBase + wcol * 64 + j * 16 + lo;
          int idx = atomicAdd(cnt, 1);
          if (idx < ncap) cand[idx] = ((u32)row << 13) | (u32)col;
        }
      }

#pragma unroll
  for (int i = 0; i < 4; ++i)
#pragma unroll
    for (int r = 0; r < 4; ++r) {
      float v = rowp[i][r];
#pragma unroll
      for (int off = 8; off; off >>= 1) v += __shfl_xor(v, off, 16);
      rowp[i][r] = v;
    }
#pragma unroll
  for (int j = 0; j < 4; ++j) {
    double v = colp[j];
    v += __shfl_xor(v, 16);
    v += __shfl_xor(v, 32);
    colp[j] = v;
  }

  if (wcol == 1 && lo == 0) {
#pragma unroll
    for (int i = 0; i < 4; ++i)
#pragma unroll
      for (int r = 0; r < 4; ++r) sR[wrow][i * 16 + quad * 4 + r] = rowp[i][r];
  }
  if (wrow == 1 && quad == 0) {
#pragma unroll
    for (int j = 0; j < 4; ++j) sC[wcol][j * 16 + lo] = colp[j];
  }
  __syncthreads();

  if (wcol == 0 && lo == 0) {
#pragma unroll
    for (int i = 0; i < 4; ++i)
#pragma unroll
      for (int r = 0; r < 4; ++r) {
        int idx = i * 16 + quad * 4 + r;
        atomicAdd(&R[rowBase + wrow * 64 + idx], (double)(rowp[i][r] + sR[wrow][idx]));
      }
  }
  if (wrow == 0 && quad == 0) {
#pragma unroll
    for (int j = 0; j < 4; ++j) {
      int idx = j * 16 + lo;
      atomicAdd(&Cmy[colBase + wcol * 64 + idx], colp[j] + sC[wcol][idx]);
    }
  }
}

// ---------------- fp32 fallback GEMM (used only if ws too small) ----------------
__global__ __launch_bounds__(256) void k_gemm_f32(
    const float* __restrict__ A, const float* __restrict__ B,
    double* __restrict__ R, double* __restrict__ CP,
    int* __restrict__ cnt, u32* __restrict__ cand, int ncap) {
  __shared__ float As[32][128];
  __shared__ float Bs[32][128];
  __shared__ double colLds[16][128];
  const int tid = threadIdx.x;
  const int tx = tid & 15, ty = tid >> 4;
  const int rowBase = blockIdx.y * 128;
  const int colBase = blockIdx.x * 128;
  float acc[8][8];
#pragma unroll
  for (int i = 0; i < 8; ++i)
#pragma unroll
    for (int j = 0; j < 8; ++j) acc[i][j] = 0.f;
  const int lr = tid >> 3;
  const int lc = (tid & 7) << 2;
  for (int kk = 0; kk < DD; kk += 32) {
#pragma unroll
    for (int r = 0; r < 4; ++r) {
      int row = lr + r * 32;
      float4 av = *(const float4*)(A + (size_t)(rowBase + row) * DD + kk + lc);
      float4 bv = *(const float4*)(B + (size_t)(colBase + row) * DD + kk + lc);
      As[lc + 0][row] = av.x; As[lc + 1][row] = av.y; As[lc + 2][row] = av.z; As[lc + 3][row] = av.w;
      Bs[lc + 0][row] = bv.x; Bs[lc + 1][row] = bv.y; Bs[lc + 2][row] = bv.z; Bs[lc + 3][row] = bv.w;
    }
    __syncthreads();
#pragma unroll 4
    for (int k = 0; k < 32; ++k) {
      float a[8], b[8];
      *(float4*)(a + 0) = *(const float4*)(&As[k][ty * 8 + 0]);
      *(float4*)(a + 4) = *(const float4*)(&As[k][ty * 8 + 4]);
      *(float4*)(b + 0) = *(const float4*)(&Bs[k][tx * 8 + 0]);
      *(float4*)(b + 4) = *(const float4*)(&Bs[k][tx * 8 + 4]);
#pragma unroll
      for (int i = 0; i < 8; ++i)
#pragma unroll
        for (int j = 0; j < 8; ++j)
          acc[i][j] = fmaf(a[i], b[j], acc[i][j]);
    }
    __syncthreads();
  }
  double colpart[8];
#pragma unroll
  for (int j = 0; j < 8; ++j) colpart[j] = 0.0;
#pragma unroll
  for (int i = 0; i < 8; ++i) {
    double rp = 0.0;
#pragma unroll
    for (int j = 0; j < 8; ++j) {
      float e = __expf(2.f * acc[i][j] - 2.f);
      rp += (double)e;
      colpart[j] += (double)e;
    }
#pragma unroll
    for (int off = 8; off; off >>= 1) rp += __shfl_down(rp, off, 16);
    if (tx == 0) atomicAdd(&R[rowBase + ty * 8 + i], rp);
  }
#pragma unroll
  for (int j = 0; j < 8; ++j) colLds[ty][tx * 8 + j] = colpart[j];
  __syncthreads();
  if (tid < 128) {
    double s = 0.0;
#pragma unroll
    for (int t = 0; t < 16; ++t) s += colLds[t][tid];
    atomicAdd(&CP[colBase + tid], s);   // partition 0 only
  }
#pragma unroll
  for (int i = 0; i < 8; ++i)
#pragma unroll
    for (int j = 0; j < 8; ++j) {
      if (acc[i][j] >= CAND_T0) {
        int idx = atomicAdd(cnt, 1);
        if (idx < ncap)
          cand[idx] = ((u32)(rowBase + ty * 8 + i) << 13) | (u32)(colBase + tx * 8 + j);
      }
    }
}

// One wave per candidate: exact fp64 dot, fp64 score, orderable u64 key.
__global__ __launch_bounds__(256) void k_score(
    const float* __restrict__ A, const float* __restrict__ B,
    const double* __restrict__ R, const double* __restrict__ CP,
    const int* __restrict__ cnt, const u32* __restrict__ cand,
    u64* __restrict__ keys, int ncap) {
  int w = (int)((blockIdx.x * 256 + threadIdx.x) >> 6);
  int lane = threadIdx.x & 63;
  int n = *cnt; if (n > ncap) n = ncap;
  if (w >= n) return;
  u32 mn = cand[w];
  int m = (int)(mn >> 13), nn = (int)(mn & 8191u);
  const float* ar = A + (size_t)m * DD;
  const float* br = B + (size_t)nn * DD;
  double s = 0.0;
#pragma unroll
  for (int d = 0; d < DD; d += 64)
    s = fma((double)ar[d + lane], (double)br[d + lane], s);
#pragma unroll
  for (int off = 32; off; off >>= 1) s += __shfl_down(s, off);
  if (lane == 0) {
    double Cn = 0.0;
#pragma unroll
    for (int x = 0; x < 8; ++x) Cn += CP[(size_t)x * ND + nn];
    double sc = exp(4.0 * s - 4.0) / (R[m] * Cn);
    keys[w] = (u64)__double_as_longlong(sc);
  }
}

// (key desc, flat-idx asc) strict order; idx unique so no true ties.
__device__ __forceinline__ bool is_worse(u64 ka, u32 ma, u64 kb, u32 mb) {
  return (ka < kb) || (ka == kb && ma > mb);
}

// Single-block top-256: register/shuffle bitonic. Fast path n<=2048, with
// dynamic merge depth (np=1024 when n<=1024 -> skip one bitonic level).
// Legacy 4096 LDS bitonic fallback.
__global__ __launch_bounds__(1024) void k_sort(
    const int* __restrict__ cnt, const u32* __restrict__ cand,
    const u64* __restrict__ keys, float* __restrict__ out, int ncap) {
  __shared__ u64 sk[NPAD];
  __shared__ u32 sm[NPAD];
  const int tid = threadIdx.x;
  const int lane = tid & 63;
  const int wid = tid >> 6;
  int m = *cnt; if (m > ncap) m = ncap;

  if (m <= 2048) {
    const int NP = (m <= 1024) ? 1024 : 2048;
    const int base = wid * 128;
    const int i0 = base + lane * 2;

    // wave-local sort of each 128-segment (reg/shuffle, zero barriers).
    // Padding segments (>= NP) sort trivially and are never merged/read.
    u64 k0 = (i0 < m) ? keys[i0] : 0;
    u64 k1 = (i0 + 1 < m) ? keys[i0 + 1] : 0;
    u32 m0 = (i0 < m) ? cand[i0] : 0xFFFFFFFFu;
    u32 m1 = (i0 + 1 < m) ? cand[i0 + 1] : 0xFFFFFFFFu;
#pragma unroll
    for (int k = 2; k <= 128; k <<= 1) {
#pragma unroll
      for (int j = k >> 1; j >= 1; j >>= 1) {
        const bool bf = ((i0 & k) == 0);
        if (j == 1) {
          bool sw = bf ? is_worse(k0, m0, k1, m1) : is_worse(k1, m1, k0, m0);
          if (sw) { u64 tk = k0; k0 = k1; k1 = tk; u32 tm = m0; m0 = m1; m1 = tm; }
        } else {
          const int j2 = j >> 1;
          const bool keepb = (bf == ((lane & j2) == 0));
          u64 pk0 = __shfl_xor(k0, j2); u32 pm0 = __shfl_xor(m0, j2);
          u64 pk1 = __shfl_xor(k1, j2); u32 pm1 = __shfl_xor(m1, j2);
          if (keepb == is_worse(k0, m0, pk0, pm0)) { k0 = pk0; m0 = pm0; }
          if (keepb == is_worse(k1, m1, pk1, pm1)) { k1 = pk1; m1 = pm1; }
        }
      }
    }
    sk[i0] = k0; sk[i0 + 1] = k1; sm[i0] = m0; sm[i0 + 1] = m1;
    __syncthreads();

    for (int k = 256; k <= NP; k <<= 1) {
      for (int j = k >> 1; j >= 128; j >>= 1) {
        for (int i = tid; i < NP; i += 1024) {
          int l = i ^ j;
          if (l > i) {
            u64 ki = sk[i], kl = sk[l];
            u32 mi = sm[i], ml = sm[l];
            bool bf = ((i & k) == 0);
            bool swp = bf ? is_worse(ki, mi, kl, ml) : is_worse(kl, ml, ki, mi);
            if (swp) { sk[i] = kl; sk[l] = ki; sm[i] = ml; sm[l] = mi; }
          }
        }
        __syncthreads();
      }
      if (i0 < NP) {
        k0 = sk[i0]; k1 = sk[i0 + 1]; m0 = sm[i0]; m1 = sm[i0 + 1];
        const bool bf = ((base & k) == 0);
#pragma unroll
        for (int j = 64; j >= 2; j >>= 1) {
          const int j2 = j >> 1;
          const bool keepb = (bf == ((lane & j2) == 0));
          u64 pk0 = __shfl_xor(k0, j2); u32 pm0 = __shfl_xor(m0, j2);
          u64 pk1 = __shfl_xor(k1, j2); u32 pm1 = __shfl_xor(m1, j2);
          if (keepb == is_worse(k0, m0, pk0, pm0)) { k0 = pk0; m0 = pm0; }
          if (keepb == is_worse(k1, m1, pk1, pm1)) { k1 = pk1; m1 = pm1; }
        }
        {
          bool sw = bf ? is_worse(k0, m0, k1, m1) : is_worse(k1, m1, k0, m0);
          if (sw) { u64 tk = k0; k0 = k1; k1 = tk; u32 tm = m0; m0 = m1; m1 = tm; }
        }
      }
      __syncthreads();
      if (i0 < NP) { sk[i0] = k0; sk[i0 + 1] = k1; sm[i0] = m0; sm[i0 + 1] = m1; }
      __syncthreads();
    }
  } else {
    for (int i = tid; i < NPAD; i += 1024) { sk[i] = 0; sm[i] = 0xFFFFFFFFu; }
    __syncthreads();
    for (int i = tid; i < m; i += 1024) { sk[i] = keys[i]; sm[i] = cand[i]; }
    __syncthreads();
    for (unsigned k = 2; k <= (unsigned)NPAD; k <<= 1) {
      for (unsigned j = k >> 1; j > 0; j >>= 1) {
        for (unsigned i = tid; i < (unsigned)NPAD; i += 1024) {
          unsigned l = i ^ j;
          if (l > i) {
            u64 ki = sk[i], kl = sk[l];
            u32 mi = sm[i], ml = sm[l];
            bool dir = ((i & k) == 0);
            bool swp = dir ? is_worse(ki, mi, kl, ml) : is_worse(kl, ml, ki, mi);
            if (swp) { sk[i] = kl; sk[l] = ki; sm[i] = ml; sm[l] = mi; }
          }
        }
        __syncthreads();
      }
    }
  }

  for (int r = tid; r < KTOP; r += 1024) {
    u32 mn = sm[r];
    u64 kk = sk[r];
    out[r] = (float)(mn >> 13);
    out[KTOP + r] = (float)(mn & 8191u);
    out[2 * KTOP + r] = (float)__longlong_as_double((long long)kk);
  }
}

extern "C" void kernel_launch(void* const* d_in, const int* in_sizes, int n_in,
                              void* d_out, int out_size, void* d_ws, size_t ws_size,
                              hipStream_t stream) {
  (void)in_sizes; (void)n_in; (void)out_size;
  const float* A = (const float*)d_in[0];  // ref_feats [8192,256]
  const float* B = (const float*)d_in[1];  // src_feats [8192,256]
  float* out = (float*)d_out;
  char* ws = (char*)d_ws;
  double* R = (double*)(ws + OFF_R);
  double* CP = (double*)(ws + OFF_CP);
  int* cnt = (int*)(ws + OFF_CNT);
  u32* cand = (u32*)(ws + OFF_CAND);
  u64* keys = (u64*)(ws + OFF_KEYS);

  if (ws_size >= (size_t)WS_REQ) {
    u16* A16p = (u16*)(ws + OFF_A16);
    u16* B16p = (u16*)(ws + OFF_B16);
    hipLaunchKernelGGL(k_prep2, dim3(2048), dim3(256), 0, stream,
                       A, B, A16p, B16p, R, CP, cnt);
    hipLaunchKernelGGL(k_gemm_mfma, dim3(4096), dim3(256), 0, stream,
                       A16p, B16p, R, CP, cnt, cand, NCAP);
  } else {
    hipLaunchKernelGGL(k_init, dim3(288), dim3(256), 0, stream, R, CP, cnt);
    hipLaunchKernelGGL(k_gemm_f32, dim3(ND / 128, MD / 128), dim3(256), 0, stream,
                       A, B, R, CP, cnt, cand, NCAP);
  }

  hipLaunchKernelGGL(k_score, dim3(NCAP / 4), dim3(256), 0, stream,
                     A, B, R, CP, cnt, cand, keys, NCAP);
  hipLaunchKernelGGL(k_sort, dim3(1), dim3(1024), 0, stream,
                     cnt, cand, keys, out, NCAP);
}